// Round 3
// baseline (2660.835 us; speedup 1.0000x reference)
//
#include <hip/hip_runtime.h>
#include <hip/hip_bf16.h>

#define B_ 8
#define N_ 1024
#define K_ 20
#define BN_ (B_*N_)

// 1/sqrt(1+1e-5)  (eval-mode BN with running_var=1)
#define BN_SCALE 0.9999950000374997f

__device__ __forceinline__ float US2F(unsigned short u) {
    union { unsigned u; float f; } c; c.u = ((unsigned)u) << 16; return c.f;
}

// ---------------------------------------------------------------- dtype detect
// gammas are ~N(1,0.1). If inputs are bf16, first u16 of each decodes into
// (0.5,1.5). If fp32, that word is random low-mantissa bits (P~0.3% in range).
__global__ void k_detect(const unsigned short* g1, const unsigned short* g2,
                         const unsigned short* g3, const unsigned short* g4,
                         const unsigned short* g5, const unsigned short* g6,
                         const unsigned short* g7, int* flag) {
    const unsigned short* gs[7] = {g1, g2, g3, g4, g5, g6, g7};
    int cnt = 0;
    for (int i = 0; i < 7; i++) {
        float v = US2F(gs[i][0]);
        if (v > 0.5f && v < 1.5f) cnt++;
    }
    *flag = (cnt >= 4) ? 1 : 0;   // 1 = bf16 inputs, 0 = fp32 inputs
}

// ---------------------------------------------------------------- prep:
// convert (+ transpose (O,I)->(I,O)) every weight/bias to fp32, either dtype.
struct TPar { const void* src; float* dst; int O, I, blk0; };
struct TList { TPar p[41]; };

__global__ __launch_bounds__(256) void k_prep(TList tl, int nent, const int* flag) {
    const int isbf = *flag;
    int blk = blockIdx.x;
    int wi = 0;
    for (int j = nent - 1; j >= 0; j--) { if (blk >= tl.p[j].blk0) { wi = j; break; } }
    const TPar p = tl.p[wi];
    int e = (blk - p.blk0) * 256 + threadIdx.x;
    int n = p.O * p.I;
    if (e >= n) return;
    int o = e / p.I, i = e - o * p.I;
    float v = isbf ? US2F(((const unsigned short*)p.src)[e])
                   : ((const float*)p.src)[e];
    p.dst[(size_t)i * p.O + o] = v;
}

// ---------------------------------------------------------------- norms
__global__ __launch_bounds__(256) void k_norms(const float* __restrict__ xf,
                                               float* __restrict__ xx, int C) {
    int i = blockIdx.x * 256 + threadIdx.x;
    if (i >= BN_) return;
    const float* p = xf + (size_t)i * C;
    float s = 0.f;
    for (int c = 0; c < C; c++) s += p[c] * p[c];
    xx[i] = s;
}

// ---------------------------------------------------------------- kNN top-20
template<int C>
__global__ __launch_bounds__(256) void k_knn(const float* __restrict__ xf,
                                             const float* __restrict__ xx,
                                             int* __restrict__ idx) {
    const int bi = blockIdx.x;
    const int b = bi >> 10, i = bi & 1023;
    const int t = threadIdx.x;
    __shared__ float pd[N_];
    __shared__ float xi[C];
    __shared__ float wv_[4];
    __shared__ int   wj_[4];
    const float* xb = xf + (size_t)b * N_ * C;
    for (int c = t; c < C; c += 256) xi[c] = xb[(size_t)i * C + c];
    __syncthreads();
    const float xxi = xx[bi];
    for (int j = t; j < N_; j += 256) {
        const float* xj = xb + (size_t)j * C;
        float dot = 0.f;
        #pragma unroll
        for (int c = 0; c < C; c++) dot += xi[c] * xj[c];
        pd[j] = 2.f * dot - xxi - xx[b * N_ + j];   // negative squared distance
    }
    __syncthreads();
    for (int kk = 0; kk < K_; kk++) {
        float bv = -3e38f; int bj = 0;
        #pragma unroll
        for (int q = 0; q < 4; q++) {
            int j = t + q * 256;
            float v = pd[j];
            if (v > bv) { bv = v; bj = j; }   // ascending scan: strict > keeps lowest j
        }
        #pragma unroll
        for (int s = 32; s > 0; s >>= 1) {
            float ov = __shfl_xor(bv, s, 64);
            int   oj = __shfl_xor(bj, s, 64);
            if (ov > bv || (ov == bv && oj < bj)) { bv = ov; bj = oj; }
        }
        if ((t & 63) == 0) { wv_[t >> 6] = bv; wj_[t >> 6] = bj; }
        __syncthreads();
        if (t == 0) {
            float fv = wv_[0]; int fj = wj_[0];
            for (int q = 1; q < 4; q++)
                if (wv_[q] > fv || (wv_[q] == fv && wj_[q] < fj)) { fv = wv_[q]; fj = wj_[q]; }
            idx[bi * K_ + kk] = fj;
            pd[fj] = -3e38f;
        }
        __syncthreads();
    }
}

// ---------------------------------------------------------------- EdgeConv
// out[bi][co] = lrelu(bn( max_k  sum_c w[co][c]*(nbr_k[c]-ctr[c]) + s2(co) ))
// (BN scale > 0 and lrelu monotone -> transform commutes with max)
template<int C, int CO>
__global__ __launch_bounds__(256) void k_edge(const float* __restrict__ xf,
                                              const int* __restrict__ idx,
                                              const float* __restrict__ wT,   // (2C, CO) fp32
                                              const float* __restrict__ g,
                                              const float* __restrict__ bb,
                                              float* __restrict__ out) {
    constexpr int TPC = CO / 4;            // threads along co (4 co each)
    constexpr int NG  = 256 / TPC;         // k-groups
    constexpr int KPT = (K_ + NG - 1) / NG;
    const int bi = blockIdx.x;
    const int b = bi >> 10, i = bi & 1023;
    const int t = threadIdx.x;
    __shared__ float ctr[C];
    __shared__ float df[K_][C];
    __shared__ float redm[NG][CO];
    const float* xb = xf + (size_t)b * N_ * C;
    for (int c = t; c < C; c += 256) ctr[c] = xb[(size_t)i * C + c];
    __syncthreads();
    for (int q = t; q < K_ * C; q += 256) {
        int kk = q / C, c = q - kk * C;
        int j = idx[bi * K_ + kk];
        df[kk][c] = xb[(size_t)j * C + c] - ctr[c];
    }
    __syncthreads();
    const int cog = (t % TPC) * 4;
    const int r   = t / TPC;
    float acc[KPT][4] = {};
    for (int c = 0; c < C; c++) {
        const float4 wv = *reinterpret_cast<const float4*>(&wT[(size_t)c * CO + cog]);
        #pragma unroll
        for (int gk = 0; gk < KPT; gk++) {
            int kk = r * KPT + gk;
            int kks = kk < K_ ? kk : K_ - 1;
            float dv = df[kks][c];
            acc[gk][0] += dv * wv.x; acc[gk][1] += dv * wv.y;
            acc[gk][2] += dv * wv.z; acc[gk][3] += dv * wv.w;
        }
    }
    float m[4] = {-3e38f, -3e38f, -3e38f, -3e38f};
    #pragma unroll
    for (int gk = 0; gk < KPT; gk++) {
        int kk = r * KPT + gk;
        if (kk < K_) {
            #pragma unroll
            for (int j = 0; j < 4; j++) m[j] = fmaxf(m[j], acc[gk][j]);
        }
    }
    #pragma unroll
    for (int j = 0; j < 4; j++) redm[r][cog + j] = m[j];
    __syncthreads();
    if (r == 0) {
        for (int rr = 1; rr < NG; rr++)
            #pragma unroll
            for (int j = 0; j < 4; j++) m[j] = fmaxf(m[j], redm[rr][cog + j]);
        // s2 = sum_c w[co][C+c] * ctr[c]
        float4 s2 = {0.f, 0.f, 0.f, 0.f};
        for (int c = 0; c < C; c++) {
            const float4 wv = *reinterpret_cast<const float4*>(&wT[(size_t)(C + c) * CO + cog]);
            float cv = ctr[c];
            s2.x += wv.x * cv; s2.y += wv.y * cv; s2.z += wv.z * cv; s2.w += wv.w * cv;
        }
        float sv[4] = {s2.x, s2.y, s2.z, s2.w};
        #pragma unroll
        for (int j = 0; j < 4; j++) {
            int co = cog + j;
            float val = m[j] + sv[j];
            float h = val * (g[co] * BN_SCALE) + bb[co];
            out[(size_t)bi * CO + co] = h >= 0.f ? h : 0.2f * h;
        }
    }
}

// ---------------------------------------------------------------- MHA over L=8 (batch axis), in-place + residual
template<int E>
__global__ __launch_bounds__(256) void k_mha(float* __restrict__ x,
                                             const float* __restrict__ wiT,  // (E, 3E) fp32
                                             const float* __restrict__ bi_,
                                             const float* __restrict__ woT,  // (E, E) fp32
                                             const float* __restrict__ bo_) {
    constexpr int L = 8, H = 4, D = E / H;
    const float qs = (D == 16) ? 0.25f : (D == 32) ? 0.17677669529663687f : 0.125f;
    const int n = blockIdx.x, t = threadIdx.x;
    __shared__ float xin[L][E];
    __shared__ float qkv[L][3 * E];
    __shared__ float o_[L][E];
    for (int u = t; u < L * E; u += 256) {
        int l = u / E, e = u - (u / E) * E;
        xin[l][e] = x[((size_t)l * N_ + n) * E + e];
    }
    __syncthreads();
    for (int u = t; u < L * 3 * E; u += 256) {
        int l = u / (3 * E), r = u - l * (3 * E);
        float acc = 0.f;
        for (int e = 0; e < E; e++) acc += xin[l][e] * wiT[(size_t)e * 3 * E + r];
        acc += bi_[r];
        if (r < E) acc *= qs;
        qkv[l][r] = acc;
    }
    __syncthreads();
    if (t < H * L) {
        int h = t >> 3, l = t & 7;
        float s[L]; float mx = -3e38f;
        for (int m = 0; m < L; m++) {
            float a = 0.f;
            for (int dd = 0; dd < D; dd++) a += qkv[l][h * D + dd] * qkv[m][E + h * D + dd];
            s[m] = a; mx = fmaxf(mx, a);
        }
        float sum = 0.f;
        for (int m = 0; m < L; m++) { s[m] = expf(s[m] - mx); sum += s[m]; }
        float inv = 1.f / sum;
        for (int dd = 0; dd < D; dd++) {
            float a = 0.f;
            for (int m = 0; m < L; m++) a += s[m] * qkv[m][2 * E + h * D + dd];
            o_[l][h * D + dd] = a * inv;
        }
    }
    __syncthreads();
    for (int u = t; u < L * E; u += 256) {
        int l = u / E, e = u - l * E;
        float acc = 0.f;
        for (int ep = 0; ep < E; ep++) acc += o_[l][ep] * woT[(size_t)ep * E + e];
        acc += bo_[e] + xin[l][e];
        x[((size_t)l * N_ + n) * E + e] = acc;
    }
}

// ---------------------------------------------------------------- conv5: cat(x1..x4) @ w5.T, BN, lrelu. 8 points/block.
__global__ __launch_bounds__(256) void k_conv5(const float* __restrict__ x1, const float* __restrict__ x2,
                                               const float* __restrict__ x3, const float* __restrict__ x4,
                                               const float* __restrict__ w5T,  // (512, 1024) fp32
                                               const float* __restrict__ g5,
                                               const float* __restrict__ b5,
                                               float* __restrict__ h5) {
    const int t = threadIdx.x;
    const int p0 = blockIdx.x * 8;
    __shared__ float cat[8][512];
    for (int u = t; u < 8 * 512; u += 256) {
        int p = u >> 9, c = u & 511;
        int pt = p0 + p;
        float v;
        if (c < 64)       v = x1[(size_t)pt * 64 + c];
        else if (c < 128) v = x2[(size_t)pt * 64 + (c - 64)];
        else if (c < 256) v = x3[(size_t)pt * 128 + (c - 128)];
        else              v = x4[(size_t)pt * 256 + (c - 256)];
        cat[p][c] = v;
    }
    __syncthreads();
    const int o = t * 4;
    float acc[8][4] = {};
    for (int c = 0; c < 512; c++) {
        const float4 wv = *reinterpret_cast<const float4*>(&w5T[(size_t)c * 1024 + o]);
        #pragma unroll
        for (int p = 0; p < 8; p++) {
            float cv = cat[p][c];
            acc[p][0] += cv * wv.x; acc[p][1] += cv * wv.y;
            acc[p][2] += cv * wv.z; acc[p][3] += cv * wv.w;
        }
    }
    #pragma unroll
    for (int p = 0; p < 8; p++) {
        #pragma unroll
        for (int j = 0; j < 4; j++) {
            int oo = o + j;
            float h = acc[p][j] * (g5[oo] * BN_SCALE) + b5[oo];
            h5[(size_t)(p0 + p) * 1024 + oo] = h >= 0.f ? h : 0.2f * h;
        }
    }
}

// ---------------------------------------------------------------- pool: max & mean over N per (b, channel)
__global__ __launch_bounds__(256) void k_pool(const float* __restrict__ h5, float* __restrict__ feat) {
    int c = blockIdx.x * 256 + threadIdx.x;   // 0..1023
    int b = blockIdx.y;
    float mx = -3e38f, sm = 0.f;
    for (int n = 0; n < N_; n++) {
        float v = h5[((size_t)b * N_ + n) * 1024 + c];
        mx = fmaxf(mx, v); sm += v;
    }
    feat[b * 2048 + c] = mx;
    feat[b * 2048 + 1024 + c] = sm * (1.f / 1024.f);
}

// ---------------------------------------------------------------- FC head
__global__ __launch_bounds__(256) void k_fc1(const float* __restrict__ feat, const float* __restrict__ l1wT,
                                             const float* __restrict__ g6, const float* __restrict__ b6,
                                             float* __restrict__ f1) {
    int b = blockIdx.x, t = threadIdx.x;
    __shared__ float fin[2048];
    for (int u = t; u < 2048; u += 256) fin[u] = feat[b * 2048 + u];
    __syncthreads();
    for (int o = t; o < 512; o += 256) {
        float acc = 0.f;
        for (int c = 0; c < 2048; c++) acc += fin[c] * l1wT[(size_t)c * 512 + o];
        float h = acc * (g6[o] * BN_SCALE) + b6[o];
        f1[b * 512 + o] = h >= 0.f ? h : 0.2f * h;
    }
}

__global__ __launch_bounds__(256) void k_fc2(const float* __restrict__ f1, const float* __restrict__ l2wT,
                                             const float* __restrict__ l2b,
                                             const float* __restrict__ g7, const float* __restrict__ b7,
                                             float* __restrict__ f2) {
    int b = blockIdx.x, t = threadIdx.x;
    __shared__ float fin[512];
    for (int u = t; u < 512; u += 256) fin[u] = f1[b * 512 + u];
    __syncthreads();
    if (t < 256) {
        int o = t;
        float acc = 0.f;
        for (int c = 0; c < 512; c++) acc += fin[c] * l2wT[(size_t)c * 256 + o];
        acc += l2b[o];
        float h = acc * (g7[o] * BN_SCALE) + b7[o];
        f2[b * 256 + o] = h >= 0.f ? h : 0.2f * h;
    }
}

__global__ __launch_bounds__(64) void k_fc3(const float* __restrict__ f2, const float* __restrict__ l3wT,
                                            const float* __restrict__ l3b,
                                            void* __restrict__ out, const int* __restrict__ flag) {
    int b = blockIdx.x, t = threadIdx.x;
    __shared__ float fin[256];
    for (int u = t; u < 256; u += 64) fin[u] = f2[b * 256 + u];
    __syncthreads();
    if (t < 40) {
        float acc = 0.f;
        for (int c = 0; c < 256; c++) acc += fin[c] * l3wT[(size_t)c * 40 + t];
        acc += l3b[t];
        if (*flag) ((__hip_bfloat16*)out)[b * 40 + t] = __float2bfloat16(acc);
        else       ((float*)out)[b * 40 + t] = acc;
    }
}

// ================================================================ host
extern "C" void kernel_launch(void* const* d_in, const int* in_sizes, int n_in,
                              void* d_out, int out_size, void* d_ws, size_t ws_size,
                              hipStream_t stream) {
    auto us = [&](int i) { return (const unsigned short*)d_in[i]; };

    float* ws = (float*)d_ws;
    size_t off = 0;
    auto A = [&](size_t n) { float* p = ws + off; off += (n + 3) & ~(size_t)3; return p; };
    float* xf0  = A((size_t)BN_ * 3);
    float* x1   = A((size_t)BN_ * 64);
    float* x2   = A((size_t)BN_ * 64);
    float* x3   = A((size_t)BN_ * 128);
    float* x4   = A((size_t)BN_ * 256);
    float* h5   = A((size_t)BN_ * 1024);
    float* feat = A(8 * 2048);
    float* f1   = A(8 * 512);
    float* f2   = A(8 * 256);
    float* xx   = A(BN_);
    int*   idx  = (int*)A((size_t)BN_ * K_);
    int*   flag = (int*)A(4);
    float* w1T   = A(6 * 64);
    float* w2T   = A(128 * 64);
    float* w3T   = A(128 * 128);
    float* w4T   = A(256 * 256);
    float* a1wiT = A(64 * 192);  float* a1woT = A(64 * 64);
    float* a2wiT = A(64 * 192);  float* a2woT = A(64 * 64);
    float* a3wiT = A(128 * 384); float* a3woT = A(128 * 128);
    float* a4wiT = A(256 * 768); float* a4woT = A(256 * 256);
    float* w5T   = A(512 * 1024);
    float* l1wT  = A(2048 * 512);
    float* l2wT  = A(512 * 256);
    float* l3wT  = A(256 * 40);
    // converted small vectors
    float* g1f = A(64);   float* b1f = A(64);
    float* g2f = A(64);   float* b2f = A(64);
    float* g3f = A(128);  float* b3f = A(128);
    float* g4f = A(256);  float* b4f = A(256);
    float* bi1 = A(192);  float* bo1 = A(64);
    float* bi2 = A(192);  float* bo2 = A(64);
    float* bi3 = A(384);  float* bo3 = A(128);
    float* bi4 = A(768);  float* bo4 = A(256);
    float* g5f = A(1024); float* b5f = A(1024);
    float* g6f = A(512);  float* b6f = A(512);
    float* l2bf = A(256);
    float* g7f = A(256);  float* b7f = A(256);
    float* l3bf = A(40);

    k_detect<<<1, 1, 0, stream>>>(us(2), us(5), us(8), us(11), us(30), us(33), us(37), flag);

    TList tl; int nb = 0; int k = 0;
    auto add = [&](int i, float* dst, int O, int I) {
        tl.p[k].src = d_in[i]; tl.p[k].dst = dst; tl.p[k].O = O; tl.p[k].I = I; tl.p[k].blk0 = nb;
        nb += (O * I + 255) / 256; k++;
    };
    add(0,  xf0,   BN_ * 3, 1);     // x convert (identity "transpose")
    add(1,  w1T,   64, 6);
    add(4,  w2T,   64, 128);
    add(7,  w3T,   128, 128);
    add(10, w4T,   256, 256);       // w4 is (256, 256): ci = 2*128
    add(13, a1wiT, 192, 64);
    add(15, a1woT, 64, 64);
    add(17, a2wiT, 192, 64);
    add(19, a2woT, 64, 64);
    add(21, a3wiT, 384, 128);
    add(23, a3woT, 128, 128);
    add(25, a4wiT, 768, 256);
    add(27, a4woT, 256, 256);
    add(29, w5T,   1024, 512);
    add(32, l1wT,  512, 2048);
    add(35, l2wT,  256, 512);
    add(39, l3wT,  40, 256);
    // vectors (identity convert)
    add(2,  g1f, 64, 1);   add(3,  b1f, 64, 1);
    add(5,  g2f, 64, 1);   add(6,  b2f, 64, 1);
    add(8,  g3f, 128, 1);  add(9,  b3f, 128, 1);
    add(11, g4f, 256, 1);  add(12, b4f, 256, 1);
    add(14, bi1, 192, 1);  add(16, bo1, 64, 1);
    add(18, bi2, 192, 1);  add(20, bo2, 64, 1);
    add(22, bi3, 384, 1);  add(24, bo3, 128, 1);
    add(26, bi4, 768, 1);  add(28, bo4, 256, 1);
    add(30, g5f, 1024, 1); add(31, b5f, 1024, 1);
    add(33, g6f, 512, 1);  add(34, b6f, 512, 1);
    add(36, l2bf, 256, 1);
    add(37, g7f, 256, 1);  add(38, b7f, 256, 1);
    add(40, l3bf, 40, 1);
    k_prep<<<nb, 256, 0, stream>>>(tl, k, flag);

    // layer 1  (C=3 -> 64)
    k_norms<<<BN_ / 256, 256, 0, stream>>>(xf0, xx, 3);
    k_knn<3><<<BN_, 256, 0, stream>>>(xf0, xx, idx);
    k_edge<3, 64><<<BN_, 256, 0, stream>>>(xf0, idx, w1T, g1f, b1f, x1);
    k_mha<64><<<N_, 256, 0, stream>>>(x1, a1wiT, bi1, a1woT, bo1);

    // layer 2  (C=64 -> 64)
    k_norms<<<BN_ / 256, 256, 0, stream>>>(x1, xx, 64);
    k_knn<64><<<BN_, 256, 0, stream>>>(x1, xx, idx);
    k_edge<64, 64><<<BN_, 256, 0, stream>>>(x1, idx, w2T, g2f, b2f, x2);
    k_mha<64><<<N_, 256, 0, stream>>>(x2, a2wiT, bi2, a2woT, bo2);

    // layer 3  (C=64 -> 128)
    k_norms<<<BN_ / 256, 256, 0, stream>>>(x2, xx, 64);
    k_knn<64><<<BN_, 256, 0, stream>>>(x2, xx, idx);
    k_edge<64, 128><<<BN_, 256, 0, stream>>>(x2, idx, w3T, g3f, b3f, x3);
    k_mha<128><<<N_, 256, 0, stream>>>(x3, a3wiT, bi3, a3woT, bo3);

    // layer 4  (C=128 -> 256)
    k_norms<<<BN_ / 256, 256, 0, stream>>>(x3, xx, 128);
    k_knn<128><<<BN_, 256, 0, stream>>>(x3, xx, idx);
    k_edge<128, 256><<<BN_, 256, 0, stream>>>(x3, idx, w4T, g4f, b4f, x4);
    k_mha<256><<<N_, 256, 0, stream>>>(x4, a4wiT, bi4, a4woT, bo4);

    // head
    k_conv5<<<BN_ / 8, 256, 0, stream>>>(x1, x2, x3, x4, w5T, g5f, b5f, h5);
    k_pool<<<dim3(4, 8), 256, 0, stream>>>(h5, feat);
    k_fc1<<<8, 256, 0, stream>>>(feat, l1wT, g6f, b6f, f1);
    k_fc2<<<8, 256, 0, stream>>>(f1, l2wT, l2bf, g7f, b7f, f2);
    k_fc3<<<8, 64, 0, stream>>>(f2, l3wT, l3bf, d_out, flag);
}

// Round 4
// 2610.531 us; speedup vs baseline: 1.0193x; 1.0193x over previous
//
#include <hip/hip_runtime.h>
#include <hip/hip_bf16.h>

#define B_ 8
#define N_ 1024
#define K_ 20
#define BN_ (B_*N_)

// 1/sqrt(1+1e-5)  (eval-mode BN with running_var=1)
#define BN_SCALE 0.9999950000374997f

__device__ __forceinline__ float US2F(unsigned short u) {
    union { unsigned u; float f; } c; c.u = ((unsigned)u) << 16; return c.f;
}

// ---------------------------------------------------------------- dtype detect
// gammas are ~N(1,0.1). If inputs are bf16, first u16 of each decodes into
// (0.5,1.5). If fp32, that word is random low-mantissa bits (P~0.3% in range).
__global__ void k_detect(const unsigned short* g1, const unsigned short* g2,
                         const unsigned short* g3, const unsigned short* g4,
                         const unsigned short* g5, const unsigned short* g6,
                         const unsigned short* g7, int* flag) {
    const unsigned short* gs[7] = {g1, g2, g3, g4, g5, g6, g7};
    int cnt = 0;
    for (int i = 0; i < 7; i++) {
        float v = US2F(gs[i][0]);
        if (v > 0.5f && v < 1.5f) cnt++;
    }
    *flag = (cnt >= 4) ? 1 : 0;   // 1 = bf16 inputs, 0 = fp32 inputs
}

// ---------------------------------------------------------------- prep:
// convert (+ transpose (O,I)->(I,O)) every weight/bias to fp32, either dtype.
struct TPar { const void* src; float* dst; int O, I, blk0; };
struct TList { TPar p[41]; };

__global__ __launch_bounds__(256) void k_prep(TList tl, int nent, const int* flag) {
    const int isbf = *flag;
    int blk = blockIdx.x;
    int wi = 0;
    for (int j = nent - 1; j >= 0; j--) { if (blk >= tl.p[j].blk0) { wi = j; break; } }
    const TPar p = tl.p[wi];
    int e = (blk - p.blk0) * 256 + threadIdx.x;
    int n = p.O * p.I;
    if (e >= n) return;
    int o = e / p.I, i = e - o * p.I;
    float v = isbf ? US2F(((const unsigned short*)p.src)[e])
                   : ((const float*)p.src)[e];
    p.dst[(size_t)i * p.O + o] = v;
}

// ---------------------------------------------------------------- norms
__global__ __launch_bounds__(256) void k_norms(const float* __restrict__ xf,
                                               float* __restrict__ xx, int C) {
    int i = blockIdx.x * 256 + threadIdx.x;
    if (i >= BN_) return;
    const float* p = xf + (size_t)i * C;
    float s = 0.f;
    for (int c = 0; c < C; c++) s += p[c] * p[c];
    xx[i] = s;
}

// ---------------------------------------------------------------- kNN top-20
// Wave-per-point: 4 waves/block = 4 points/block. 1024 distances live in
// registers (16/lane, j = q*64+lane). Top-20 = 20 rounds of local argmax +
// 6-step shuffle butterfly; NO __syncthreads in the loop (the R3 kernel's
// 40 barriers/block were 80% of total runtime at VALUBusy=16%).
template<int C>
__global__ __launch_bounds__(256) void k_knn(const float* __restrict__ xf,
                                             const float* __restrict__ xx,
                                             int* __restrict__ idx) {
    const int w    = threadIdx.x >> 6;
    const int lane = threadIdx.x & 63;
    const int bi   = blockIdx.x * 4 + w;       // point id 0..8191
    const int b = bi >> 10, i = bi & 1023;
    const float* xb  = xf + (size_t)b * N_ * C;
    const float* xxb = xx + (size_t)b * N_;

    __shared__ float xi[4][C];
    for (int c = lane; c < C; c += 64) xi[w][c] = xb[(size_t)i * C + c];
    __syncthreads();   // single barrier (cross-lane LDS visibility)

    const float xxi = xxb[i];
    float d[16];
    #pragma unroll 4
    for (int q = 0; q < 16; q++) {
        const int j = q * 64 + lane;
        const float* xj = xb + (size_t)j * C;
        float dot = 0.f;
        #pragma unroll
        for (int c4 = 0; c4 < C / 4; c4++) {
            const float4 xv = *reinterpret_cast<const float4*>(xj + c4 * 4);
            const float4 iv = *reinterpret_cast<const float4*>(&xi[w][c4 * 4]);
            dot += xv.x * iv.x + xv.y * iv.y + xv.z * iv.z + xv.w * iv.w;
        }
        #pragma unroll
        for (int c = (C / 4) * 4; c < C; c++) dot += xj[c] * xi[w][c];
        d[q] = 2.f * dot - xxi - xxb[j];        // negative squared distance
    }

    int myj = 0;
    for (int kk = 0; kk < K_; kk++) {
        // local argmax over 16 regs (strict > keeps lowest q -> lowest j)
        float v = d[0]; int q = 0;
        #pragma unroll
        for (int t = 1; t < 16; t++) if (d[t] > v) { v = d[t]; q = t; }
        int j = q * 64 + lane;
        // butterfly allreduce: max value, lowest index on ties
        #pragma unroll
        for (int s = 1; s < 64; s <<= 1) {
            float ov = __shfl_xor(v, s, 64);
            int   oj = __shfl_xor(j, s, 64);
            if (ov > v || (ov == v && oj < j)) { v = ov; j = oj; }
        }
        if (lane == kk) myj = j;
        // clear the winner (predicated unrolled write: no scratch spill)
        const bool mine = (j & 63) == lane;
        const int  wq   = j >> 6;
        #pragma unroll
        for (int t = 0; t < 16; t++) d[t] = (mine && wq == t) ? -3e38f : d[t];
    }
    if (lane < K_) idx[bi * K_ + lane] = myj;
}

// ---------------------------------------------------------------- EdgeConv
// out[bi][co] = lrelu(bn( max_k  sum_c w[co][c]*(nbr_k[c]-ctr[c]) + s2(co) ))
// (BN scale > 0 and lrelu monotone -> transform commutes with max)
template<int C, int CO>
__global__ __launch_bounds__(256) void k_edge(const float* __restrict__ xf,
                                              const int* __restrict__ idx,
                                              const float* __restrict__ wT,   // (2C, CO) fp32
                                              const float* __restrict__ g,
                                              const float* __restrict__ bb,
                                              float* __restrict__ out) {
    constexpr int TPC = CO / 4;            // threads along co (4 co each)
    constexpr int NG  = 256 / TPC;         // k-groups
    constexpr int KPT = (K_ + NG - 1) / NG;
    const int bi = blockIdx.x;
    const int b = bi >> 10, i = bi & 1023;
    const int t = threadIdx.x;
    __shared__ float ctr[C];
    __shared__ float df[K_][C];
    __shared__ float redm[NG][CO];
    const float* xb = xf + (size_t)b * N_ * C;
    for (int c = t; c < C; c += 256) ctr[c] = xb[(size_t)i * C + c];
    __syncthreads();
    for (int q = t; q < K_ * C; q += 256) {
        int kk = q / C, c = q - kk * C;
        int j = idx[bi * K_ + kk];
        df[kk][c] = xb[(size_t)j * C + c] - ctr[c];
    }
    __syncthreads();
    const int cog = (t % TPC) * 4;
    const int r   = t / TPC;
    float acc[KPT][4] = {};
    for (int c = 0; c < C; c++) {
        const float4 wv = *reinterpret_cast<const float4*>(&wT[(size_t)c * CO + cog]);
        #pragma unroll
        for (int gk = 0; gk < KPT; gk++) {
            int kk = r * KPT + gk;
            int kks = kk < K_ ? kk : K_ - 1;
            float dv = df[kks][c];
            acc[gk][0] += dv * wv.x; acc[gk][1] += dv * wv.y;
            acc[gk][2] += dv * wv.z; acc[gk][3] += dv * wv.w;
        }
    }
    float m[4] = {-3e38f, -3e38f, -3e38f, -3e38f};
    #pragma unroll
    for (int gk = 0; gk < KPT; gk++) {
        int kk = r * KPT + gk;
        if (kk < K_) {
            #pragma unroll
            for (int j = 0; j < 4; j++) m[j] = fmaxf(m[j], acc[gk][j]);
        }
    }
    #pragma unroll
    for (int j = 0; j < 4; j++) redm[r][cog + j] = m[j];
    __syncthreads();
    if (r == 0) {
        for (int rr = 1; rr < NG; rr++)
            #pragma unroll
            for (int j = 0; j < 4; j++) m[j] = fmaxf(m[j], redm[rr][cog + j]);
        // s2 = sum_c w[co][C+c] * ctr[c]
        float4 s2 = {0.f, 0.f, 0.f, 0.f};
        for (int c = 0; c < C; c++) {
            const float4 wv = *reinterpret_cast<const float4*>(&wT[(size_t)(C + c) * CO + cog]);
            float cv = ctr[c];
            s2.x += wv.x * cv; s2.y += wv.y * cv; s2.z += wv.z * cv; s2.w += wv.w * cv;
        }
        float sv[4] = {s2.x, s2.y, s2.z, s2.w};
        #pragma unroll
        for (int j = 0; j < 4; j++) {
            int co = cog + j;
            float val = m[j] + sv[j];
            float h = val * (g[co] * BN_SCALE) + bb[co];
            out[(size_t)bi * CO + co] = h >= 0.f ? h : 0.2f * h;
        }
    }
}

// ---------------------------------------------------------------- MHA over L=8 (batch axis), in-place + residual
template<int E>
__global__ __launch_bounds__(256) void k_mha(float* __restrict__ x,
                                             const float* __restrict__ wiT,  // (E, 3E) fp32
                                             const float* __restrict__ bi_,
                                             const float* __restrict__ woT,  // (E, E) fp32
                                             const float* __restrict__ bo_) {
    constexpr int L = 8, H = 4, D = E / H;
    const float qs = (D == 16) ? 0.25f : (D == 32) ? 0.17677669529663687f : 0.125f;
    const int n = blockIdx.x, t = threadIdx.x;
    __shared__ float xin[L][E];
    __shared__ float qkv[L][3 * E];
    __shared__ float o_[L][E];
    for (int u = t; u < L * E; u += 256) {
        int l = u / E, e = u - (u / E) * E;
        xin[l][e] = x[((size_t)l * N_ + n) * E + e];
    }
    __syncthreads();
    for (int u = t; u < L * 3 * E; u += 256) {
        int l = u / (3 * E), r = u - l * (3 * E);
        float acc = 0.f;
        for (int e = 0; e < E; e++) acc += xin[l][e] * wiT[(size_t)e * 3 * E + r];
        acc += bi_[r];
        if (r < E) acc *= qs;
        qkv[l][r] = acc;
    }
    __syncthreads();
    if (t < H * L) {
        int h = t >> 3, l = t & 7;
        float s[L]; float mx = -3e38f;
        for (int m = 0; m < L; m++) {
            float a = 0.f;
            for (int dd = 0; dd < D; dd++) a += qkv[l][h * D + dd] * qkv[m][E + h * D + dd];
            s[m] = a; mx = fmaxf(mx, a);
        }
        float sum = 0.f;
        for (int m = 0; m < L; m++) { s[m] = expf(s[m] - mx); sum += s[m]; }
        float inv = 1.f / sum;
        for (int dd = 0; dd < D; dd++) {
            float a = 0.f;
            for (int m = 0; m < L; m++) a += s[m] * qkv[m][2 * E + h * D + dd];
            o_[l][h * D + dd] = a * inv;
        }
    }
    __syncthreads();
    for (int u = t; u < L * E; u += 256) {
        int l = u / E, e = u - l * E;
        float acc = 0.f;
        for (int ep = 0; ep < E; ep++) acc += o_[l][ep] * woT[(size_t)ep * E + e];
        acc += bo_[e] + xin[l][e];
        x[((size_t)l * N_ + n) * E + e] = acc;
    }
}

// ---------------------------------------------------------------- conv5: cat(x1..x4) @ w5.T, BN, lrelu. 8 points/block.
__global__ __launch_bounds__(256) void k_conv5(const float* __restrict__ x1, const float* __restrict__ x2,
                                               const float* __restrict__ x3, const float* __restrict__ x4,
                                               const float* __restrict__ w5T,  // (512, 1024) fp32
                                               const float* __restrict__ g5,
                                               const float* __restrict__ b5,
                                               float* __restrict__ h5) {
    const int t = threadIdx.x;
    const int p0 = blockIdx.x * 8;
    __shared__ float cat[8][512];
    for (int u = t; u < 8 * 512; u += 256) {
        int p = u >> 9, c = u & 511;
        int pt = p0 + p;
        float v;
        if (c < 64)       v = x1[(size_t)pt * 64 + c];
        else if (c < 128) v = x2[(size_t)pt * 64 + (c - 64)];
        else if (c < 256) v = x3[(size_t)pt * 128 + (c - 128)];
        else              v = x4[(size_t)pt * 256 + (c - 256)];
        cat[p][c] = v;
    }
    __syncthreads();
    const int o = t * 4;
    float acc[8][4] = {};
    for (int c = 0; c < 512; c++) {
        const float4 wv = *reinterpret_cast<const float4*>(&w5T[(size_t)c * 1024 + o]);
        #pragma unroll
        for (int p = 0; p < 8; p++) {
            float cv = cat[p][c];
            acc[p][0] += cv * wv.x; acc[p][1] += cv * wv.y;
            acc[p][2] += cv * wv.z; acc[p][3] += cv * wv.w;
        }
    }
    #pragma unroll
    for (int p = 0; p < 8; p++) {
        #pragma unroll
        for (int j = 0; j < 4; j++) {
            int oo = o + j;
            float h = acc[p][j] * (g5[oo] * BN_SCALE) + b5[oo];
            h5[(size_t)(p0 + p) * 1024 + oo] = h >= 0.f ? h : 0.2f * h;
        }
    }
}

// ---------------------------------------------------------------- pool: max & mean over N per (b, channel)
__global__ __launch_bounds__(256) void k_pool(const float* __restrict__ h5, float* __restrict__ feat) {
    int c = blockIdx.x * 256 + threadIdx.x;   // 0..1023
    int b = blockIdx.y;
    float mx = -3e38f, sm = 0.f;
    for (int n = 0; n < N_; n++) {
        float v = h5[((size_t)b * N_ + n) * 1024 + c];
        mx = fmaxf(mx, v); sm += v;
    }
    feat[b * 2048 + c] = mx;
    feat[b * 2048 + 1024 + c] = sm * (1.f / 1024.f);
}

// ---------------------------------------------------------------- FC head
__global__ __launch_bounds__(256) void k_fc1(const float* __restrict__ feat, const float* __restrict__ l1wT,
                                             const float* __restrict__ g6, const float* __restrict__ b6,
                                             float* __restrict__ f1) {
    int b = blockIdx.x, t = threadIdx.x;
    __shared__ float fin[2048];
    for (int u = t; u < 2048; u += 256) fin[u] = feat[b * 2048 + u];
    __syncthreads();
    for (int o = t; o < 512; o += 256) {
        float acc = 0.f;
        for (int c = 0; c < 2048; c++) acc += fin[c] * l1wT[(size_t)c * 512 + o];
        float h = acc * (g6[o] * BN_SCALE) + b6[o];
        f1[b * 512 + o] = h >= 0.f ? h : 0.2f * h;
    }
}

__global__ __launch_bounds__(256) void k_fc2(const float* __restrict__ f1, const float* __restrict__ l2wT,
                                             const float* __restrict__ l2b,
                                             const float* __restrict__ g7, const float* __restrict__ b7,
                                             float* __restrict__ f2) {
    int b = blockIdx.x, t = threadIdx.x;
    __shared__ float fin[512];
    for (int u = t; u < 512; u += 256) fin[u] = f1[b * 512 + u];
    __syncthreads();
    if (t < 256) {
        int o = t;
        float acc = 0.f;
        for (int c = 0; c < 512; c++) acc += fin[c] * l2wT[(size_t)c * 256 + o];
        acc += l2b[o];
        float h = acc * (g7[o] * BN_SCALE) + b7[o];
        f2[b * 256 + o] = h >= 0.f ? h : 0.2f * h;
    }
}

__global__ __launch_bounds__(64) void k_fc3(const float* __restrict__ f2, const float* __restrict__ l3wT,
                                            const float* __restrict__ l3b,
                                            void* __restrict__ out, const int* __restrict__ flag) {
    int b = blockIdx.x, t = threadIdx.x;
    __shared__ float fin[256];
    for (int u = t; u < 256; u += 64) fin[u] = f2[b * 256 + u];
    __syncthreads();
    if (t < 40) {
        float acc = 0.f;
        for (int c = 0; c < 256; c++) acc += fin[c] * l3wT[(size_t)c * 40 + t];
        acc += l3b[t];
        if (*flag) ((__hip_bfloat16*)out)[b * 40 + t] = __float2bfloat16(acc);
        else       ((float*)out)[b * 40 + t] = acc;
    }
}

// ================================================================ host
extern "C" void kernel_launch(void* const* d_in, const int* in_sizes, int n_in,
                              void* d_out, int out_size, void* d_ws, size_t ws_size,
                              hipStream_t stream) {
    auto us = [&](int i) { return (const unsigned short*)d_in[i]; };

    float* ws = (float*)d_ws;
    size_t off = 0;
    auto A = [&](size_t n) { float* p = ws + off; off += (n + 3) & ~(size_t)3; return p; };
    float* xf0  = A((size_t)BN_ * 3);
    float* x1   = A((size_t)BN_ * 64);
    float* x2   = A((size_t)BN_ * 64);
    float* x3   = A((size_t)BN_ * 128);
    float* x4   = A((size_t)BN_ * 256);
    float* h5   = A((size_t)BN_ * 1024);
    float* feat = A(8 * 2048);
    float* f1   = A(8 * 512);
    float* f2   = A(8 * 256);
    float* xx   = A(BN_);
    int*   idx  = (int*)A((size_t)BN_ * K_);
    int*   flag = (int*)A(4);
    float* w1T   = A(6 * 64);
    float* w2T   = A(128 * 64);
    float* w3T   = A(128 * 128);
    float* w4T   = A(256 * 256);
    float* a1wiT = A(64 * 192);  float* a1woT = A(64 * 64);
    float* a2wiT = A(64 * 192);  float* a2woT = A(64 * 64);
    float* a3wiT = A(128 * 384); float* a3woT = A(128 * 128);
    float* a4wiT = A(256 * 768); float* a4woT = A(256 * 256);
    float* w5T   = A(512 * 1024);
    float* l1wT  = A(2048 * 512);
    float* l2wT  = A(512 * 256);
    float* l3wT  = A(256 * 40);
    // converted small vectors
    float* g1f = A(64);   float* b1f = A(64);
    float* g2f = A(64);   float* b2f = A(64);
    float* g3f = A(128);  float* b3f = A(128);
    float* g4f = A(256);  float* b4f = A(256);
    float* bi1 = A(192);  float* bo1 = A(64);
    float* bi2 = A(192);  float* bo2 = A(64);
    float* bi3 = A(384);  float* bo3 = A(128);
    float* bi4 = A(768);  float* bo4 = A(256);
    float* g5f = A(1024); float* b5f = A(1024);
    float* g6f = A(512);  float* b6f = A(512);
    float* l2bf = A(256);
    float* g7f = A(256);  float* b7f = A(256);
    float* l3bf = A(40);

    k_detect<<<1, 1, 0, stream>>>(us(2), us(5), us(8), us(11), us(30), us(33), us(37), flag);

    TList tl; int nb = 0; int k = 0;
    auto add = [&](int i, float* dst, int O, int I) {
        tl.p[k].src = d_in[i]; tl.p[k].dst = dst; tl.p[k].O = O; tl.p[k].I = I; tl.p[k].blk0 = nb;
        nb += (O * I + 255) / 256; k++;
    };
    add(0,  xf0,   BN_ * 3, 1);     // x convert (identity "transpose")
    add(1,  w1T,   64, 6);
    add(4,  w2T,   64, 128);
    add(7,  w3T,   128, 128);
    add(10, w4T,   256, 256);       // w4 is (256, 256): ci = 2*128
    add(13, a1wiT, 192, 64);
    add(15, a1woT, 64, 64);
    add(17, a2wiT, 192, 64);
    add(19, a2woT, 64, 64);
    add(21, a3wiT, 384, 128);
    add(23, a3woT, 128, 128);
    add(25, a4wiT, 768, 256);
    add(27, a4woT, 256, 256);
    add(29, w5T,   1024, 512);
    add(32, l1wT,  512, 2048);
    add(35, l2wT,  256, 512);
    add(39, l3wT,  40, 256);
    // vectors (identity convert)
    add(2,  g1f, 64, 1);   add(3,  b1f, 64, 1);
    add(5,  g2f, 64, 1);   add(6,  b2f, 64, 1);
    add(8,  g3f, 128, 1);  add(9,  b3f, 128, 1);
    add(11, g4f, 256, 1);  add(12, b4f, 256, 1);
    add(14, bi1, 192, 1);  add(16, bo1, 64, 1);
    add(18, bi2, 192, 1);  add(20, bo2, 64, 1);
    add(22, bi3, 384, 1);  add(24, bo3, 128, 1);
    add(26, bi4, 768, 1);  add(28, bo4, 256, 1);
    add(30, g5f, 1024, 1); add(31, b5f, 1024, 1);
    add(33, g6f, 512, 1);  add(34, b6f, 512, 1);
    add(36, l2bf, 256, 1);
    add(37, g7f, 256, 1);  add(38, b7f, 256, 1);
    add(40, l3bf, 40, 1);
    k_prep<<<nb, 256, 0, stream>>>(tl, k, flag);

    // layer 1  (C=3 -> 64)
    k_norms<<<BN_ / 256, 256, 0, stream>>>(xf0, xx, 3);
    k_knn<3><<<BN_ / 4, 256, 0, stream>>>(xf0, xx, idx);
    k_edge<3, 64><<<BN_, 256, 0, stream>>>(xf0, idx, w1T, g1f, b1f, x1);
    k_mha<64><<<N_, 256, 0, stream>>>(x1, a1wiT, bi1, a1woT, bo1);

    // layer 2  (C=64 -> 64)
    k_norms<<<BN_ / 256, 256, 0, stream>>>(x1, xx, 64);
    k_knn<64><<<BN_ / 4, 256, 0, stream>>>(x1, xx, idx);
    k_edge<64, 64><<<BN_, 256, 0, stream>>>(x1, idx, w2T, g2f, b2f, x2);
    k_mha<64><<<N_, 256, 0, stream>>>(x2, a2wiT, bi2, a2woT, bo2);

    // layer 3  (C=64 -> 128)
    k_norms<<<BN_ / 256, 256, 0, stream>>>(x2, xx, 64);
    k_knn<64><<<BN_ / 4, 256, 0, stream>>>(x2, xx, idx);
    k_edge<64, 128><<<BN_, 256, 0, stream>>>(x2, idx, w3T, g3f, b3f, x3);
    k_mha<128><<<N_, 256, 0, stream>>>(x3, a3wiT, bi3, a3woT, bo3);

    // layer 4  (C=128 -> 256)
    k_norms<<<BN_ / 256, 256, 0, stream>>>(x3, xx, 128);
    k_knn<128><<<BN_ / 4, 256, 0, stream>>>(x3, xx, idx);
    k_edge<128, 256><<<BN_, 256, 0, stream>>>(x3, idx, w4T, g4f, b4f, x4);
    k_mha<256><<<N_, 256, 0, stream>>>(x4, a4wiT, bi4, a4woT, bo4);

    // head
    k_conv5<<<BN_ / 8, 256, 0, stream>>>(x1, x2, x3, x4, w5T, g5f, b5f, h5);
    k_pool<<<dim3(4, 8), 256, 0, stream>>>(h5, feat);
    k_fc1<<<8, 256, 0, stream>>>(feat, l1wT, g6f, b6f, f1);
    k_fc2<<<8, 256, 0, stream>>>(f1, l2wT, l2bf, g7f, b7f, f2);
    k_fc3<<<8, 64, 0, stream>>>(f2, l3wT, l3bf, d_out, flag);
}

// Round 5
// 2469.051 us; speedup vs baseline: 1.0777x; 1.0573x over previous
//
#include <hip/hip_runtime.h>
#include <hip/hip_bf16.h>

#define B_ 8
#define N_ 1024
#define K_ 20
#define BN_ (B_*N_)

// 1/sqrt(1+1e-5)  (eval-mode BN with running_var=1)
#define BN_SCALE 0.9999950000374997f

__device__ __forceinline__ float US2F(unsigned short u) {
    union { unsigned u; float f; } c; c.u = ((unsigned)u) << 16; return c.f;
}

// ---------------------------------------------------------------- dtype detect
// gammas are ~N(1,0.1). If inputs are bf16, first u16 of each decodes into
// (0.5,1.5). If fp32, that word is random low-mantissa bits (P~0.3% in range).
__global__ void k_detect(const unsigned short* g1, const unsigned short* g2,
                         const unsigned short* g3, const unsigned short* g4,
                         const unsigned short* g5, const unsigned short* g6,
                         const unsigned short* g7, int* flag) {
    const unsigned short* gs[7] = {g1, g2, g3, g4, g5, g6, g7};
    int cnt = 0;
    for (int i = 0; i < 7; i++) {
        float v = US2F(gs[i][0]);
        if (v > 0.5f && v < 1.5f) cnt++;
    }
    *flag = (cnt >= 4) ? 1 : 0;   // 1 = bf16 inputs, 0 = fp32 inputs
}

// ---------------------------------------------------------------- prep:
// convert (+ transpose (O,I)->(I,O)) every weight/bias to fp32, either dtype.
struct TPar { const void* src; float* dst; int O, I, blk0; };
struct TList { TPar p[41]; };

__global__ __launch_bounds__(256) void k_prep(TList tl, int nent, const int* flag) {
    const int isbf = *flag;
    int blk = blockIdx.x;
    int wi = 0;
    for (int j = nent - 1; j >= 0; j--) { if (blk >= tl.p[j].blk0) { wi = j; break; } }
    const TPar p = tl.p[wi];
    int e = (blk - p.blk0) * 256 + threadIdx.x;
    int n = p.O * p.I;
    if (e >= n) return;
    int o = e / p.I, i = e - o * p.I;
    float v = isbf ? US2F(((const unsigned short*)p.src)[e])
                   : ((const float*)p.src)[e];
    p.dst[(size_t)i * p.O + o] = v;
}

// ---------------------------------------------------------------- norms
__global__ __launch_bounds__(256) void k_norms(const float* __restrict__ xf,
                                               float* __restrict__ xx, int C) {
    int i = blockIdx.x * 256 + threadIdx.x;
    if (i >= BN_) return;
    const float* p = xf + (size_t)i * C;
    float s = 0.f;
    for (int c = 0; c < C; c++) s += p[c] * p[c];
    xx[i] = s;
}

// ---------------------------------------------------------------- kNN top-20
// Wave-per-point, 4 blocks/CU (launch_bounds caps VGPR<=128; the R4 version's
// 196 VGPRs dropped occupancy to 1 block/CU and exposed the selection chain).
// Selection round = value-only fmax butterfly (6 shuffles) + 16 ballots +
// scalar ffs to recover the lowest-j winner (lax.top_k tie semantics).
template<int C>
__global__ __launch_bounds__(256, 4) void k_knn(const float* __restrict__ xf,
                                                const float* __restrict__ xx,
                                                int* __restrict__ idx) {
    const int w    = threadIdx.x >> 6;
    const int lane = threadIdx.x & 63;
    const int bi   = blockIdx.x * 4 + w;       // point id 0..8191
    const int b = bi >> 10, i = bi & 1023;
    const float* xb  = xf + (size_t)b * N_ * C;
    const float* xxb = xx + (size_t)b * N_;

    __shared__ float xi[4][C];
    for (int c = lane; c < C; c += 64) xi[w][c] = xb[(size_t)i * C + c];
    __syncthreads();

    const float xxi = xxb[i];
    float d[16];
    #pragma unroll 2
    for (int q = 0; q < 16; q++) {
        const int j = q * 64 + lane;
        const float* xj = xb + (size_t)j * C;
        float dot = 0.f;
        #pragma unroll 4
        for (int c4 = 0; c4 < C / 4; c4++) {
            const float4 xv = *reinterpret_cast<const float4*>(xj + c4 * 4);
            const float4 iv = *reinterpret_cast<const float4*>(&xi[w][c4 * 4]);
            dot += xv.x * iv.x + xv.y * iv.y + xv.z * iv.z + xv.w * iv.w;
        }
        #pragma unroll
        for (int c = (C / 4) * 4; c < C; c++) dot += xj[c] * xi[w][c];
        d[q] = 2.f * dot - xxi - xxb[j];        // negative squared distance
    }

    int myj = 0;
    for (int kk = 0; kk < K_; kk++) {
        // lane-local max of 16 (value only)
        float v = d[0];
        #pragma unroll
        for (int t = 1; t < 16; t++) v = fmaxf(v, d[t]);
        // wave-wide max (value-only butterfly: 1 shuffle/step)
        #pragma unroll
        for (int s = 1; s < 64; s <<= 1) v = fmaxf(v, __shfl_xor(v, s, 64));
        // recover lowest j with d == v via ballots (wave-uniform result)
        int jw = -1;
        #pragma unroll
        for (int t = 0; t < 16; t++) {
            unsigned long long m = __ballot(d[t] == v);
            if (jw < 0 && m != 0ULL) jw = t * 64 + (int)__ffsll((long long)m) - 1;
        }
        if (jw < 0) jw = 0;                    // unreachable guard
        if (lane == kk) myj = jw;
        // clear the winner
        const int wq = jw >> 6, wl = jw & 63;
        #pragma unroll
        for (int t = 0; t < 16; t++)
            if (t == wq && lane == wl) d[t] = -3e38f;
    }
    if (lane < K_) idx[bi * K_ + lane] = myj;
}

// ---------------------------------------------------------------- EdgeConv
// out[bi][co] = lrelu(bn( max_k  sum_c w[co][c]*(nbr_k[c]-ctr[c]) + s2(co) ))
// (BN scale > 0 and lrelu monotone -> transform commutes with max)
template<int C, int CO>
__global__ __launch_bounds__(256) void k_edge(const float* __restrict__ xf,
                                              const int* __restrict__ idx,
                                              const float* __restrict__ wT,   // (2C, CO) fp32
                                              const float* __restrict__ g,
                                              const float* __restrict__ bb,
                                              float* __restrict__ out) {
    constexpr int TPC = CO / 4;            // threads along co (4 co each)
    constexpr int NG  = 256 / TPC;         // k-groups
    constexpr int KPT = (K_ + NG - 1) / NG;
    const int bi = blockIdx.x;
    const int b = bi >> 10, i = bi & 1023;
    const int t = threadIdx.x;
    __shared__ float ctr[C];
    __shared__ float df[K_][C];
    __shared__ float redm[NG][CO];
    const float* xb = xf + (size_t)b * N_ * C;
    for (int c = t; c < C; c += 256) ctr[c] = xb[(size_t)i * C + c];
    __syncthreads();
    for (int q = t; q < K_ * C; q += 256) {
        int kk = q / C, c = q - kk * C;
        int j = idx[bi * K_ + kk];
        df[kk][c] = xb[(size_t)j * C + c] - ctr[c];
    }
    __syncthreads();
    const int cog = (t % TPC) * 4;
    const int r   = t / TPC;
    float acc[KPT][4] = {};
    for (int c = 0; c < C; c++) {
        const float4 wv = *reinterpret_cast<const float4*>(&wT[(size_t)c * CO + cog]);
        #pragma unroll
        for (int gk = 0; gk < KPT; gk++) {
            int kk = r * KPT + gk;
            int kks = kk < K_ ? kk : K_ - 1;
            float dv = df[kks][c];
            acc[gk][0] += dv * wv.x; acc[gk][1] += dv * wv.y;
            acc[gk][2] += dv * wv.z; acc[gk][3] += dv * wv.w;
        }
    }
    float m[4] = {-3e38f, -3e38f, -3e38f, -3e38f};
    #pragma unroll
    for (int gk = 0; gk < KPT; gk++) {
        int kk = r * KPT + gk;
        if (kk < K_) {
            #pragma unroll
            for (int j = 0; j < 4; j++) m[j] = fmaxf(m[j], acc[gk][j]);
        }
    }
    #pragma unroll
    for (int j = 0; j < 4; j++) redm[r][cog + j] = m[j];
    __syncthreads();
    if (r == 0) {
        for (int rr = 1; rr < NG; rr++)
            #pragma unroll
            for (int j = 0; j < 4; j++) m[j] = fmaxf(m[j], redm[rr][cog + j]);
        // s2 = sum_c w[co][C+c] * ctr[c]
        float4 s2 = {0.f, 0.f, 0.f, 0.f};
        for (int c = 0; c < C; c++) {
            const float4 wv = *reinterpret_cast<const float4*>(&wT[(size_t)(C + c) * CO + cog]);
            float cv = ctr[c];
            s2.x += wv.x * cv; s2.y += wv.y * cv; s2.z += wv.z * cv; s2.w += wv.w * cv;
        }
        float sv[4] = {s2.x, s2.y, s2.z, s2.w};
        #pragma unroll
        for (int j = 0; j < 4; j++) {
            int co = cog + j;
            float val = m[j] + sv[j];
            float h = val * (g[co] * BN_SCALE) + bb[co];
            out[(size_t)bi * CO + co] = h >= 0.f ? h : 0.2f * h;
        }
    }
}

// ---------------------------------------------------------------- MHA over L=8 (batch axis), in-place + residual
template<int E>
__global__ __launch_bounds__(256) void k_mha(float* __restrict__ x,
                                             const float* __restrict__ wiT,  // (E, 3E) fp32
                                             const float* __restrict__ bi_,
                                             const float* __restrict__ woT,  // (E, E) fp32
                                             const float* __restrict__ bo_) {
    constexpr int L = 8, H = 4, D = E / H;
    const float qs = (D == 16) ? 0.25f : (D == 32) ? 0.17677669529663687f : 0.125f;
    const int n = blockIdx.x, t = threadIdx.x;
    __shared__ float xin[L][E];
    __shared__ float qkv[L][3 * E];
    __shared__ float o_[L][E];
    for (int u = t; u < L * E; u += 256) {
        int l = u / E, e = u - (u / E) * E;
        xin[l][e] = x[((size_t)l * N_ + n) * E + e];
    }
    __syncthreads();
    for (int u = t; u < L * 3 * E; u += 256) {
        int l = u / (3 * E), r = u - l * (3 * E);
        float acc = 0.f;
        for (int e = 0; e < E; e++) acc += xin[l][e] * wiT[(size_t)e * 3 * E + r];
        acc += bi_[r];
        if (r < E) acc *= qs;
        qkv[l][r] = acc;
    }
    __syncthreads();
    if (t < H * L) {
        int h = t >> 3, l = t & 7;
        float s[L]; float mx = -3e38f;
        for (int m = 0; m < L; m++) {
            float a = 0.f;
            for (int dd = 0; dd < D; dd++) a += qkv[l][h * D + dd] * qkv[m][E + h * D + dd];
            s[m] = a; mx = fmaxf(mx, a);
        }
        float sum = 0.f;
        for (int m = 0; m < L; m++) { s[m] = expf(s[m] - mx); sum += s[m]; }
        float inv = 1.f / sum;
        for (int dd = 0; dd < D; dd++) {
            float a = 0.f;
            for (int m = 0; m < L; m++) a += s[m] * qkv[m][2 * E + h * D + dd];
            o_[l][h * D + dd] = a * inv;
        }
    }
    __syncthreads();
    for (int u = t; u < L * E; u += 256) {
        int l = u / E, e = u - l * E;
        float acc = 0.f;
        for (int ep = 0; ep < E; ep++) acc += o_[l][ep] * woT[(size_t)ep * E + e];
        acc += bo_[e] + xin[l][e];
        x[((size_t)l * N_ + n) * E + e] = acc;
    }
}

// ---------------------------------------------------------------- conv5: cat(x1..x4) @ w5.T, BN, lrelu. 8 points/block.
__global__ __launch_bounds__(256) void k_conv5(const float* __restrict__ x1, const float* __restrict__ x2,
                                               const float* __restrict__ x3, const float* __restrict__ x4,
                                               const float* __restrict__ w5T,  // (512, 1024) fp32
                                               const float* __restrict__ g5,
                                               const float* __restrict__ b5,
                                               float* __restrict__ h5) {
    const int t = threadIdx.x;
    const int p0 = blockIdx.x * 8;
    __shared__ float cat[8][512];
    for (int u = t; u < 8 * 512; u += 256) {
        int p = u >> 9, c = u & 511;
        int pt = p0 + p;
        float v;
        if (c < 64)       v = x1[(size_t)pt * 64 + c];
        else if (c < 128) v = x2[(size_t)pt * 64 + (c - 64)];
        else if (c < 256) v = x3[(size_t)pt * 128 + (c - 128)];
        else              v = x4[(size_t)pt * 256 + (c - 256)];
        cat[p][c] = v;
    }
    __syncthreads();
    const int o = t * 4;
    float acc[8][4] = {};
    for (int c = 0; c < 512; c++) {
        const float4 wv = *reinterpret_cast<const float4*>(&w5T[(size_t)c * 1024 + o]);
        #pragma unroll
        for (int p = 0; p < 8; p++) {
            float cv = cat[p][c];
            acc[p][0] += cv * wv.x; acc[p][1] += cv * wv.y;
            acc[p][2] += cv * wv.z; acc[p][3] += cv * wv.w;
        }
    }
    #pragma unroll
    for (int p = 0; p < 8; p++) {
        #pragma unroll
        for (int j = 0; j < 4; j++) {
            int oo = o + j;
            float h = acc[p][j] * (g5[oo] * BN_SCALE) + b5[oo];
            h5[(size_t)(p0 + p) * 1024 + oo] = h >= 0.f ? h : 0.2f * h;
        }
    }
}

// ---------------------------------------------------------------- pool: max & mean over N per (b, channel)
__global__ __launch_bounds__(256) void k_pool(const float* __restrict__ h5, float* __restrict__ feat) {
    int c = blockIdx.x * 256 + threadIdx.x;   // 0..1023
    int b = blockIdx.y;
    float mx = -3e38f, sm = 0.f;
    for (int n = 0; n < N_; n++) {
        float v = h5[((size_t)b * N_ + n) * 1024 + c];
        mx = fmaxf(mx, v); sm += v;
    }
    feat[b * 2048 + c] = mx;
    feat[b * 2048 + 1024 + c] = sm * (1.f / 1024.f);
}

// ---------------------------------------------------------------- FC head
__global__ __launch_bounds__(256) void k_fc1(const float* __restrict__ feat, const float* __restrict__ l1wT,
                                             const float* __restrict__ g6, const float* __restrict__ b6,
                                             float* __restrict__ f1) {
    int b = blockIdx.x, t = threadIdx.x;
    __shared__ float fin[2048];
    for (int u = t; u < 2048; u += 256) fin[u] = feat[b * 2048 + u];
    __syncthreads();
    for (int o = t; o < 512; o += 256) {
        float acc = 0.f;
        for (int c = 0; c < 2048; c++) acc += fin[c] * l1wT[(size_t)c * 512 + o];
        float h = acc * (g6[o] * BN_SCALE) + b6[o];
        f1[b * 512 + o] = h >= 0.f ? h : 0.2f * h;
    }
}

__global__ __launch_bounds__(256) void k_fc2(const float* __restrict__ f1, const float* __restrict__ l2wT,
                                             const float* __restrict__ l2b,
                                             const float* __restrict__ g7, const float* __restrict__ b7,
                                             float* __restrict__ f2) {
    int b = blockIdx.x, t = threadIdx.x;
    __shared__ float fin[512];
    for (int u = t; u < 512; u += 256) fin[u] = f1[b * 512 + u];
    __syncthreads();
    if (t < 256) {
        int o = t;
        float acc = 0.f;
        for (int c = 0; c < 512; c++) acc += fin[c] * l2wT[(size_t)c * 256 + o];
        acc += l2b[o];
        float h = acc * (g7[o] * BN_SCALE) + b7[o];
        f2[b * 256 + o] = h >= 0.f ? h : 0.2f * h;
    }
}

__global__ __launch_bounds__(64) void k_fc3(const float* __restrict__ f2, const float* __restrict__ l3wT,
                                            const float* __restrict__ l3b,
                                            void* __restrict__ out, const int* __restrict__ flag) {
    int b = blockIdx.x, t = threadIdx.x;
    __shared__ float fin[256];
    for (int u = t; u < 256; u += 64) fin[u] = f2[b * 256 + u];
    __syncthreads();
    if (t < 40) {
        float acc = 0.f;
        for (int c = 0; c < 256; c++) acc += fin[c] * l3wT[(size_t)c * 40 + t];
        acc += l3b[t];
        if (*flag) ((__hip_bfloat16*)out)[b * 40 + t] = __float2bfloat16(acc);
        else       ((float*)out)[b * 40 + t] = acc;
    }
}

// ================================================================ host
extern "C" void kernel_launch(void* const* d_in, const int* in_sizes, int n_in,
                              void* d_out, int out_size, void* d_ws, size_t ws_size,
                              hipStream_t stream) {
    auto us = [&](int i) { return (const unsigned short*)d_in[i]; };

    float* ws = (float*)d_ws;
    size_t off = 0;
    auto A = [&](size_t n) { float* p = ws + off; off += (n + 3) & ~(size_t)3; return p; };
    float* xf0  = A((size_t)BN_ * 3);
    float* x1   = A((size_t)BN_ * 64);
    float* x2   = A((size_t)BN_ * 64);
    float* x3   = A((size_t)BN_ * 128);
    float* x4   = A((size_t)BN_ * 256);
    float* h5   = A((size_t)BN_ * 1024);
    float* feat = A(8 * 2048);
    float* f1   = A(8 * 512);
    float* f2   = A(8 * 256);
    float* xx   = A(BN_);
    int*   idx  = (int*)A((size_t)BN_ * K_);
    int*   flag = (int*)A(4);
    float* w1T   = A(6 * 64);
    float* w2T   = A(128 * 64);
    float* w3T   = A(128 * 128);
    float* w4T   = A(256 * 256);
    float* a1wiT = A(64 * 192);  float* a1woT = A(64 * 64);
    float* a2wiT = A(64 * 192);  float* a2woT = A(64 * 64);
    float* a3wiT = A(128 * 384); float* a3woT = A(128 * 128);
    float* a4wiT = A(256 * 768); float* a4woT = A(256 * 256);
    float* w5T   = A(512 * 1024);
    float* l1wT  = A(2048 * 512);
    float* l2wT  = A(512 * 256);
    float* l3wT  = A(256 * 40);
    // converted small vectors
    float* g1f = A(64);   float* b1f = A(64);
    float* g2f = A(64);   float* b2f = A(64);
    float* g3f = A(128);  float* b3f = A(128);
    float* g4f = A(256);  float* b4f = A(256);
    float* bi1 = A(192);  float* bo1 = A(64);
    float* bi2 = A(192);  float* bo2 = A(64);
    float* bi3 = A(384);  float* bo3 = A(128);
    float* bi4 = A(768);  float* bo4 = A(256);
    float* g5f = A(1024); float* b5f = A(1024);
    float* g6f = A(512);  float* b6f = A(512);
    float* l2bf = A(256);
    float* g7f = A(256);  float* b7f = A(256);
    float* l3bf = A(40);

    k_detect<<<1, 1, 0, stream>>>(us(2), us(5), us(8), us(11), us(30), us(33), us(37), flag);

    TList tl; int nb = 0; int k = 0;
    auto add = [&](int i, float* dst, int O, int I) {
        tl.p[k].src = d_in[i]; tl.p[k].dst = dst; tl.p[k].O = O; tl.p[k].I = I; tl.p[k].blk0 = nb;
        nb += (O * I + 255) / 256; k++;
    };
    add(0,  xf0,   BN_ * 3, 1);     // x convert (identity "transpose")
    add(1,  w1T,   64, 6);
    add(4,  w2T,   64, 128);
    add(7,  w3T,   128, 128);
    add(10, w4T,   256, 256);       // w4 is (256, 256): ci = 2*128
    add(13, a1wiT, 192, 64);
    add(15, a1woT, 64, 64);
    add(17, a2wiT, 192, 64);
    add(19, a2woT, 64, 64);
    add(21, a3wiT, 384, 128);
    add(23, a3woT, 128, 128);
    add(25, a4wiT, 768, 256);
    add(27, a4woT, 256, 256);
    add(29, w5T,   1024, 512);
    add(32, l1wT,  512, 2048);
    add(35, l2wT,  256, 512);
    add(39, l3wT,  40, 256);
    // vectors (identity convert)
    add(2,  g1f, 64, 1);   add(3,  b1f, 64, 1);
    add(5,  g2f, 64, 1);   add(6,  b2f, 64, 1);
    add(8,  g3f, 128, 1);  add(9,  b3f, 128, 1);
    add(11, g4f, 256, 1);  add(12, b4f, 256, 1);
    add(14, bi1, 192, 1);  add(16, bo1, 64, 1);
    add(18, bi2, 192, 1);  add(20, bo2, 64, 1);
    add(22, bi3, 384, 1);  add(24, bo3, 128, 1);
    add(26, bi4, 768, 1);  add(28, bo4, 256, 1);
    add(30, g5f, 1024, 1); add(31, b5f, 1024, 1);
    add(33, g6f, 512, 1);  add(34, b6f, 512, 1);
    add(36, l2bf, 256, 1);
    add(37, g7f, 256, 1);  add(38, b7f, 256, 1);
    add(40, l3bf, 40, 1);
    k_prep<<<nb, 256, 0, stream>>>(tl, k, flag);

    // layer 1  (C=3 -> 64)
    k_norms<<<BN_ / 256, 256, 0, stream>>>(xf0, xx, 3);
    k_knn<3><<<BN_ / 4, 256, 0, stream>>>(xf0, xx, idx);
    k_edge<3, 64><<<BN_, 256, 0, stream>>>(xf0, idx, w1T, g1f, b1f, x1);
    k_mha<64><<<N_, 256, 0, stream>>>(x1, a1wiT, bi1, a1woT, bo1);

    // layer 2  (C=64 -> 64)
    k_norms<<<BN_ / 256, 256, 0, stream>>>(x1, xx, 64);
    k_knn<64><<<BN_ / 4, 256, 0, stream>>>(x1, xx, idx);
    k_edge<64, 64><<<BN_, 256, 0, stream>>>(x1, idx, w2T, g2f, b2f, x2);
    k_mha<64><<<N_, 256, 0, stream>>>(x2, a2wiT, bi2, a2woT, bo2);

    // layer 3  (C=64 -> 128)
    k_norms<<<BN_ / 256, 256, 0, stream>>>(x2, xx, 64);
    k_knn<64><<<BN_ / 4, 256, 0, stream>>>(x2, xx, idx);
    k_edge<64, 128><<<BN_, 256, 0, stream>>>(x2, idx, w3T, g3f, b3f, x3);
    k_mha<128><<<N_, 256, 0, stream>>>(x3, a3wiT, bi3, a3woT, bo3);

    // layer 4  (C=128 -> 256)
    k_norms<<<BN_ / 256, 256, 0, stream>>>(x3, xx, 128);
    k_knn<128><<<BN_ / 4, 256, 0, stream>>>(x3, xx, idx);
    k_edge<128, 256><<<BN_, 256, 0, stream>>>(x3, idx, w4T, g4f, b4f, x4);
    k_mha<256><<<N_, 256, 0, stream>>>(x4, a4wiT, bi4, a4woT, bo4);

    // head
    k_conv5<<<BN_ / 8, 256, 0, stream>>>(x1, x2, x3, x4, w5T, g5f, b5f, h5);
    k_pool<<<dim3(4, 8), 256, 0, stream>>>(h5, feat);
    k_fc1<<<8, 256, 0, stream>>>(feat, l1wT, g6f, b6f, f1);
    k_fc2<<<8, 256, 0, stream>>>(f1, l2wT, l2bf, g7f, b7f, f2);
    k_fc3<<<8, 64, 0, stream>>>(f2, l3wT, l3bf, d_out, flag);
}

// Round 6
// 2124.736 us; speedup vs baseline: 1.2523x; 1.1621x over previous
//
#include <hip/hip_runtime.h>
#include <hip/hip_bf16.h>

#define B_ 8
#define N_ 1024
#define K_ 20
#define BN_ (B_*N_)

// 1/sqrt(1+1e-5)  (eval-mode BN with running_var=1)
#define BN_SCALE 0.9999950000374997f

__device__ __forceinline__ float US2F(unsigned short u) {
    union { unsigned u; float f; } c; c.u = ((unsigned)u) << 16; return c.f;
}

// ---------------------------------------------------------------- dtype detect
__global__ void k_detect(const unsigned short* g1, const unsigned short* g2,
                         const unsigned short* g3, const unsigned short* g4,
                         const unsigned short* g5, const unsigned short* g6,
                         const unsigned short* g7, int* flag) {
    const unsigned short* gs[7] = {g1, g2, g3, g4, g5, g6, g7};
    int cnt = 0;
    for (int i = 0; i < 7; i++) {
        float v = US2F(gs[i][0]);
        if (v > 0.5f && v < 1.5f) cnt++;
    }
    *flag = (cnt >= 4) ? 1 : 0;   // 1 = bf16 inputs, 0 = fp32 inputs
}

// ---------------------------------------------------------------- prep:
// convert (+ transpose (O,I)->(I,O)) every weight/bias to fp32, either dtype.
struct TPar { const void* src; float* dst; int O, I, blk0; };
struct TList { TPar p[41]; };

__global__ __launch_bounds__(256) void k_prep(TList tl, int nent, const int* flag) {
    const int isbf = *flag;
    int blk = blockIdx.x;
    int wi = 0;
    for (int j = nent - 1; j >= 0; j--) { if (blk >= tl.p[j].blk0) { wi = j; break; } }
    const TPar p = tl.p[wi];
    int e = (blk - p.blk0) * 256 + threadIdx.x;
    int n = p.O * p.I;
    if (e >= n) return;
    int o = e / p.I, i = e - o * p.I;
    float v = isbf ? US2F(((const unsigned short*)p.src)[e])
                   : ((const float*)p.src)[e];
    p.dst[(size_t)i * p.O + o] = v;
}

// ---------------------------------------------------------------- norms
__global__ __launch_bounds__(256) void k_norms(const float* __restrict__ xf,
                                               float* __restrict__ xx, int C) {
    int i = blockIdx.x * 256 + threadIdx.x;
    if (i >= BN_) return;
    const float* p = xf + (size_t)i * C;
    float s = 0.f;
    for (int c = 0; c < C; c++) s += p[c] * p[c];
    xx[i] = s;
}

// ---------------------------------------------------------------- kNN top-20
// Block = 16 points (4 waves x 4 points), same batch. Distances via LDS
// tiling: the R3/R4/R5 versions all read xj rows with lane-varying row
// index -> every global load split 64 ways in L1 (~1M line transactions
// per CU = the whole 486us). Here X[jtile] is staged coalesced into LDS
// (+1 pad: bank = (lane+c)%32, 2 lanes/bank = free), each lane then does
// 1 ds_read_b32 + 1 broadcast b128 per 4 FMAs. Selection = ballot scheme.
template<int C>
__global__ __launch_bounds__(256, 3) void k_knn(const float* __restrict__ xf,
                                                const float* __restrict__ xx,
                                                int* __restrict__ idx) {
    const int t = threadIdx.x;
    const int w = t >> 6, lane = t & 63;
    const int pbase = blockIdx.x * 16;
    const int b = pbase >> 10, i0 = pbase & 1023;
    const float* xb  = xf + (size_t)b * N_ * C;
    const float* xxb = xx + (size_t)b * N_;

    __shared__ float xt[64][C + 1];
    __shared__ float ct[C][16];

    for (int u = t; u < 16 * C; u += 256) {
        int p = u / C, c = u - p * C;
        ct[c][p] = xb[(size_t)(i0 + p) * C + c];
    }

    float xxi[4];
    #pragma unroll
    for (int pp = 0; pp < 4; pp++) xxi[pp] = xxb[i0 + w * 4 + pp];

    float d[4][16];
    for (int q = 0; q < 16; q++) {
        __syncthreads();
        for (int u = t; u < 64 * C; u += 256) {
            int r = u / C, c = u - r * C;
            xt[r][c] = xb[(size_t)(q * 64 + r) * C + c];
        }
        __syncthreads();
        float a0 = 0.f, a1 = 0.f, a2 = 0.f, a3 = 0.f;
        #pragma unroll 4
        for (int c = 0; c < C; c++) {
            const float xjc = xt[lane][c];
            const float4 cv = *reinterpret_cast<const float4*>(&ct[c][w * 4]);
            a0 += xjc * cv.x; a1 += xjc * cv.y; a2 += xjc * cv.z; a3 += xjc * cv.w;
        }
        const float xxj = xxb[q * 64 + lane];
        d[0][q] = 2.f * a0 - xxi[0] - xxj;
        d[1][q] = 2.f * a1 - xxi[1] - xxj;
        d[2][q] = 2.f * a2 - xxi[2] - xxj;
        d[3][q] = 2.f * a3 - xxi[3] - xxj;
    }

    int myj[4] = {0, 0, 0, 0};
    #pragma unroll
    for (int pp = 0; pp < 4; pp++) {
        for (int kk = 0; kk < K_; kk++) {
            float v = d[pp][0];
            #pragma unroll
            for (int u = 1; u < 16; u++) v = fmaxf(v, d[pp][u]);
            #pragma unroll
            for (int s = 1; s < 64; s <<= 1) v = fmaxf(v, __shfl_xor(v, s, 64));
            int jw = -1;
            #pragma unroll
            for (int u = 0; u < 16; u++) {
                unsigned long long m = __ballot(d[pp][u] == v);
                if (jw < 0 && m != 0ULL) jw = u * 64 + (int)__ffsll((long long)m) - 1;
            }
            if (jw < 0) jw = 0;                    // unreachable guard
            if (lane == kk) myj[pp] = jw;
            const int wq = jw >> 6, wl = jw & 63;
            #pragma unroll
            for (int u = 0; u < 16; u++)
                if (u == wq && lane == wl) d[pp][u] = -3e38f;
        }
    }
    #pragma unroll
    for (int pp = 0; pp < 4; pp++)
        if (lane < K_) idx[(size_t)(pbase + w * 4 + pp) * K_ + lane] = myj[pp];
}

// ---------------------------------------------------------------- EdgeConv
// out[bi][co] = lrelu(bn( max_k  sum_c w[co][c]*(nbr_k[c]-ctr[c]) + s2(co) ))
// (BN scale > 0 and lrelu monotone -> transform commutes with max)
template<int C, int CO>
__global__ __launch_bounds__(256) void k_edge(const float* __restrict__ xf,
                                              const int* __restrict__ idx,
                                              const float* __restrict__ wT,   // (2C, CO) fp32
                                              const float* __restrict__ g,
                                              const float* __restrict__ bb,
                                              float* __restrict__ out) {
    constexpr int TPC = CO / 4;            // threads along co (4 co each)
    constexpr int NG  = 256 / TPC;         // k-groups
    constexpr int KPT = (K_ + NG - 1) / NG;
    const int bi = blockIdx.x;
    const int b = bi >> 10, i = bi & 1023;
    const int t = threadIdx.x;
    __shared__ float ctr[C];
    __shared__ float df[K_][C];
    __shared__ float redm[NG][CO];
    const float* xb = xf + (size_t)b * N_ * C;
    for (int c = t; c < C; c += 256) ctr[c] = xb[(size_t)i * C + c];
    __syncthreads();
    for (int q = t; q < K_ * C; q += 256) {
        int kk = q / C, c = q - kk * C;
        int j = idx[bi * K_ + kk];
        df[kk][c] = xb[(size_t)j * C + c] - ctr[c];
    }
    __syncthreads();
    const int cog = (t % TPC) * 4;
    const int r   = t / TPC;
    float acc[KPT][4] = {};
    for (int c = 0; c < C; c++) {
        const float4 wv = *reinterpret_cast<const float4*>(&wT[(size_t)c * CO + cog]);
        #pragma unroll
        for (int gk = 0; gk < KPT; gk++) {
            int kk = r * KPT + gk;
            int kks = kk < K_ ? kk : K_ - 1;
            float dv = df[kks][c];
            acc[gk][0] += dv * wv.x; acc[gk][1] += dv * wv.y;
            acc[gk][2] += dv * wv.z; acc[gk][3] += dv * wv.w;
        }
    }
    float m[4] = {-3e38f, -3e38f, -3e38f, -3e38f};
    #pragma unroll
    for (int gk = 0; gk < KPT; gk++) {
        int kk = r * KPT + gk;
        if (kk < K_) {
            #pragma unroll
            for (int j = 0; j < 4; j++) m[j] = fmaxf(m[j], acc[gk][j]);
        }
    }
    #pragma unroll
    for (int j = 0; j < 4; j++) redm[r][cog + j] = m[j];
    __syncthreads();
    if (r == 0) {
        for (int rr = 1; rr < NG; rr++)
            #pragma unroll
            for (int j = 0; j < 4; j++) m[j] = fmaxf(m[j], redm[rr][cog + j]);
        // s2 = sum_c w[co][C+c] * ctr[c]
        float4 s2 = {0.f, 0.f, 0.f, 0.f};
        for (int c = 0; c < C; c++) {
            const float4 wv = *reinterpret_cast<const float4*>(&wT[(size_t)(C + c) * CO + cog]);
            float cv = ctr[c];
            s2.x += wv.x * cv; s2.y += wv.y * cv; s2.z += wv.z * cv; s2.w += wv.w * cv;
        }
        float sv[4] = {s2.x, s2.y, s2.z, s2.w};
        #pragma unroll
        for (int j = 0; j < 4; j++) {
            int co = cog + j;
            float val = m[j] + sv[j];
            float h = val * (g[co] * BN_SCALE) + bb[co];
            out[(size_t)bi * CO + co] = h >= 0.f ? h : 0.2f * h;
        }
    }
}

// ---------------------------------------------------------------- MHA over L=8 (batch axis), in-place + residual
template<int E>
__global__ __launch_bounds__(256) void k_mha(float* __restrict__ x,
                                             const float* __restrict__ wiT,  // (E, 3E) fp32
                                             const float* __restrict__ bi_,
                                             const float* __restrict__ woT,  // (E, E) fp32
                                             const float* __restrict__ bo_) {
    constexpr int L = 8, H = 4, D = E / H;
    const float qs = (D == 16) ? 0.25f : (D == 32) ? 0.17677669529663687f : 0.125f;
    const int n = blockIdx.x, t = threadIdx.x;
    __shared__ float xin[L][E];
    __shared__ float qkv[L][3 * E];
    __shared__ float o_[L][E];
    for (int u = t; u < L * E; u += 256) {
        int l = u / E, e = u - (u / E) * E;
        xin[l][e] = x[((size_t)l * N_ + n) * E + e];
    }
    __syncthreads();
    for (int u = t; u < L * 3 * E; u += 256) {
        int l = u / (3 * E), r = u - l * (3 * E);
        float acc = 0.f;
        for (int e = 0; e < E; e++) acc += xin[l][e] * wiT[(size_t)e * 3 * E + r];
        acc += bi_[r];
        if (r < E) acc *= qs;
        qkv[l][r] = acc;
    }
    __syncthreads();
    if (t < H * L) {
        int h = t >> 3, l = t & 7;
        float s[L]; float mx = -3e38f;
        for (int m = 0; m < L; m++) {
            float a = 0.f;
            for (int dd = 0; dd < D; dd++) a += qkv[l][h * D + dd] * qkv[m][E + h * D + dd];
            s[m] = a; mx = fmaxf(mx, a);
        }
        float sum = 0.f;
        for (int m = 0; m < L; m++) { s[m] = expf(s[m] - mx); sum += s[m]; }
        float inv = 1.f / sum;
        for (int dd = 0; dd < D; dd++) {
            float a = 0.f;
            for (int m = 0; m < L; m++) a += s[m] * qkv[m][2 * E + h * D + dd];
            o_[l][h * D + dd] = a * inv;
        }
    }
    __syncthreads();
    for (int u = t; u < L * E; u += 256) {
        int l = u / E, e = u - l * E;
        float acc = 0.f;
        for (int ep = 0; ep < E; ep++) acc += o_[l][ep] * woT[(size_t)ep * E + e];
        acc += bo_[e] + xin[l][e];
        x[((size_t)l * N_ + n) * E + e] = acc;
    }
}

// ---------------------------------------------------------------- conv5: cat(x1..x4) @ w5.T, BN, lrelu. 8 points/block.
__global__ __launch_bounds__(256) void k_conv5(const float* __restrict__ x1, const float* __restrict__ x2,
                                               const float* __restrict__ x3, const float* __restrict__ x4,
                                               const float* __restrict__ w5T,  // (512, 1024) fp32
                                               const float* __restrict__ g5,
                                               const float* __restrict__ b5,
                                               float* __restrict__ h5) {
    const int t = threadIdx.x;
    const int p0 = blockIdx.x * 8;
    __shared__ float cat[8][512];
    for (int u = t; u < 8 * 512; u += 256) {
        int p = u >> 9, c = u & 511;
        int pt = p0 + p;
        float v;
        if (c < 64)       v = x1[(size_t)pt * 64 + c];
        else if (c < 128) v = x2[(size_t)pt * 64 + (c - 64)];
        else if (c < 256) v = x3[(size_t)pt * 128 + (c - 128)];
        else              v = x4[(size_t)pt * 256 + (c - 256)];
        cat[p][c] = v;
    }
    __syncthreads();
    const int o = t * 4;
    float acc[8][4] = {};
    for (int c = 0; c < 512; c++) {
        const float4 wv = *reinterpret_cast<const float4*>(&w5T[(size_t)c * 1024 + o]);
        #pragma unroll
        for (int p = 0; p < 8; p++) {
            float cv = cat[p][c];
            acc[p][0] += cv * wv.x; acc[p][1] += cv * wv.y;
            acc[p][2] += cv * wv.z; acc[p][3] += cv * wv.w;
        }
    }
    #pragma unroll
    for (int p = 0; p < 8; p++) {
        #pragma unroll
        for (int j = 0; j < 4; j++) {
            int oo = o + j;
            float h = acc[p][j] * (g5[oo] * BN_SCALE) + b5[oo];
            h5[(size_t)(p0 + p) * 1024 + oo] = h >= 0.f ? h : 0.2f * h;
        }
    }
}

// ---------------------------------------------------------------- pool: max & mean over N per (b, channel)
__global__ __launch_bounds__(256) void k_pool(const float* __restrict__ h5, float* __restrict__ feat) {
    int c = blockIdx.x * 256 + threadIdx.x;   // 0..1023
    int b = blockIdx.y;
    float mx = -3e38f, sm = 0.f;
    for (int n = 0; n < N_; n++) {
        float v = h5[((size_t)b * N_ + n) * 1024 + c];
        mx = fmaxf(mx, v); sm += v;
    }
    feat[b * 2048 + c] = mx;
    feat[b * 2048 + 1024 + c] = sm * (1.f / 1024.f);
}

// ---------------------------------------------------------------- FC head
__global__ __launch_bounds__(256) void k_fc1(const float* __restrict__ feat, const float* __restrict__ l1wT,
                                             const float* __restrict__ g6, const float* __restrict__ b6,
                                             float* __restrict__ f1) {
    int b = blockIdx.x, t = threadIdx.x;
    __shared__ float fin[2048];
    for (int u = t; u < 2048; u += 256) fin[u] = feat[b * 2048 + u];
    __syncthreads();
    for (int o = t; o < 512; o += 256) {
        float acc = 0.f;
        for (int c = 0; c < 2048; c++) acc += fin[c] * l1wT[(size_t)c * 512 + o];
        float h = acc * (g6[o] * BN_SCALE) + b6[o];
        f1[b * 512 + o] = h >= 0.f ? h : 0.2f * h;
    }
}

__global__ __launch_bounds__(256) void k_fc2(const float* __restrict__ f1, const float* __restrict__ l2wT,
                                             const float* __restrict__ l2b,
                                             const float* __restrict__ g7, const float* __restrict__ b7,
                                             float* __restrict__ f2) {
    int b = blockIdx.x, t = threadIdx.x;
    __shared__ float fin[512];
    for (int u = t; u < 512; u += 256) fin[u] = f1[b * 512 + u];
    __syncthreads();
    if (t < 256) {
        int o = t;
        float acc = 0.f;
        for (int c = 0; c < 512; c++) acc += fin[c] * l2wT[(size_t)c * 256 + o];
        acc += l2b[o];
        float h = acc * (g7[o] * BN_SCALE) + b7[o];
        f2[b * 256 + o] = h >= 0.f ? h : 0.2f * h;
    }
}

__global__ __launch_bounds__(64) void k_fc3(const float* __restrict__ f2, const float* __restrict__ l3wT,
                                            const float* __restrict__ l3b,
                                            void* __restrict__ out, const int* __restrict__ flag) {
    int b = blockIdx.x, t = threadIdx.x;
    __shared__ float fin[256];
    for (int u = t; u < 256; u += 64) fin[u] = f2[b * 256 + u];
    __syncthreads();
    if (t < 40) {
        float acc = 0.f;
        for (int c = 0; c < 256; c++) acc += fin[c] * l3wT[(size_t)c * 40 + t];
        acc += l3b[t];
        if (*flag) ((__hip_bfloat16*)out)[b * 40 + t] = __float2bfloat16(acc);
        else       ((float*)out)[b * 40 + t] = acc;
    }
}

// ================================================================ host
extern "C" void kernel_launch(void* const* d_in, const int* in_sizes, int n_in,
                              void* d_out, int out_size, void* d_ws, size_t ws_size,
                              hipStream_t stream) {
    auto us = [&](int i) { return (const unsigned short*)d_in[i]; };

    float* ws = (float*)d_ws;
    size_t off = 0;
    auto A = [&](size_t n) { float* p = ws + off; off += (n + 3) & ~(size_t)3; return p; };
    float* xf0  = A((size_t)BN_ * 3);
    float* x1   = A((size_t)BN_ * 64);
    float* x2   = A((size_t)BN_ * 64);
    float* x3   = A((size_t)BN_ * 128);
    float* x4   = A((size_t)BN_ * 256);
    float* h5   = A((size_t)BN_ * 1024);
    float* feat = A(8 * 2048);
    float* f1   = A(8 * 512);
    float* f2   = A(8 * 256);
    float* xx   = A(BN_);
    int*   idx  = (int*)A((size_t)BN_ * K_);
    int*   flag = (int*)A(4);
    float* w1T   = A(6 * 64);
    float* w2T   = A(128 * 64);
    float* w3T   = A(128 * 128);
    float* w4T   = A(256 * 256);
    float* a1wiT = A(64 * 192);  float* a1woT = A(64 * 64);
    float* a2wiT = A(64 * 192);  float* a2woT = A(64 * 64);
    float* a3wiT = A(128 * 384); float* a3woT = A(128 * 128);
    float* a4wiT = A(256 * 768); float* a4woT = A(256 * 256);
    float* w5T   = A(512 * 1024);
    float* l1wT  = A(2048 * 512);
    float* l2wT  = A(512 * 256);
    float* l3wT  = A(256 * 40);
    // converted small vectors
    float* g1f = A(64);   float* b1f = A(64);
    float* g2f = A(64);   float* b2f = A(64);
    float* g3f = A(128);  float* b3f = A(128);
    float* g4f = A(256);  float* b4f = A(256);
    float* bi1 = A(192);  float* bo1 = A(64);
    float* bi2 = A(192);  float* bo2 = A(64);
    float* bi3 = A(384);  float* bo3 = A(128);
    float* bi4 = A(768);  float* bo4 = A(256);
    float* g5f = A(1024); float* b5f = A(1024);
    float* g6f = A(512);  float* b6f = A(512);
    float* l2bf = A(256);
    float* g7f = A(256);  float* b7f = A(256);
    float* l3bf = A(40);

    k_detect<<<1, 1, 0, stream>>>(us(2), us(5), us(8), us(11), us(30), us(33), us(37), flag);

    TList tl; int nb = 0; int k = 0;
    auto add = [&](int i, float* dst, int O, int I) {
        tl.p[k].src = d_in[i]; tl.p[k].dst = dst; tl.p[k].O = O; tl.p[k].I = I; tl.p[k].blk0 = nb;
        nb += (O * I + 255) / 256; k++;
    };
    add(0,  xf0,   BN_ * 3, 1);     // x convert (identity "transpose")
    add(1,  w1T,   64, 6);
    add(4,  w2T,   64, 128);
    add(7,  w3T,   128, 128);
    add(10, w4T,   256, 256);       // w4 is (256, 256): ci = 2*128
    add(13, a1wiT, 192, 64);
    add(15, a1woT, 64, 64);
    add(17, a2wiT, 192, 64);
    add(19, a2woT, 64, 64);
    add(21, a3wiT, 384, 128);
    add(23, a3woT, 128, 128);
    add(25, a4wiT, 768, 256);
    add(27, a4woT, 256, 256);
    add(29, w5T,   1024, 512);
    add(32, l1wT,  512, 2048);
    add(35, l2wT,  256, 512);
    add(39, l3wT,  40, 256);
    // vectors (identity convert)
    add(2,  g1f, 64, 1);   add(3,  b1f, 64, 1);
    add(5,  g2f, 64, 1);   add(6,  b2f, 64, 1);
    add(8,  g3f, 128, 1);  add(9,  b3f, 128, 1);
    add(11, g4f, 256, 1);  add(12, b4f, 256, 1);
    add(14, bi1, 192, 1);  add(16, bo1, 64, 1);
    add(18, bi2, 192, 1);  add(20, bo2, 64, 1);
    add(22, bi3, 384, 1);  add(24, bo3, 128, 1);
    add(26, bi4, 768, 1);  add(28, bo4, 256, 1);
    add(30, g5f, 1024, 1); add(31, b5f, 1024, 1);
    add(33, g6f, 512, 1);  add(34, b6f, 512, 1);
    add(36, l2bf, 256, 1);
    add(37, g7f, 256, 1);  add(38, b7f, 256, 1);
    add(40, l3bf, 40, 1);
    k_prep<<<nb, 256, 0, stream>>>(tl, k, flag);

    // layer 1  (C=3 -> 64)
    k_norms<<<BN_ / 256, 256, 0, stream>>>(xf0, xx, 3);
    k_knn<3><<<BN_ / 16, 256, 0, stream>>>(xf0, xx, idx);
    k_edge<3, 64><<<BN_, 256, 0, stream>>>(xf0, idx, w1T, g1f, b1f, x1);
    k_mha<64><<<N_, 256, 0, stream>>>(x1, a1wiT, bi1, a1woT, bo1);

    // layer 2  (C=64 -> 64)
    k_norms<<<BN_ / 256, 256, 0, stream>>>(x1, xx, 64);
    k_knn<64><<<BN_ / 16, 256, 0, stream>>>(x1, xx, idx);
    k_edge<64, 64><<<BN_, 256, 0, stream>>>(x1, idx, w2T, g2f, b2f, x2);
    k_mha<64><<<N_, 256, 0, stream>>>(x2, a2wiT, bi2, a2woT, bo2);

    // layer 3  (C=64 -> 128)
    k_norms<<<BN_ / 256, 256, 0, stream>>>(x2, xx, 64);
    k_knn<64><<<BN_ / 16, 256, 0, stream>>>(x2, xx, idx);
    k_edge<64, 128><<<BN_, 256, 0, stream>>>(x2, idx, w3T, g3f, b3f, x3);
    k_mha<128><<<N_, 256, 0, stream>>>(x3, a3wiT, bi3, a3woT, bo3);

    // layer 4  (C=128 -> 256)
    k_norms<<<BN_ / 256, 256, 0, stream>>>(x3, xx, 128);
    k_knn<128><<<BN_ / 16, 256, 0, stream>>>(x3, xx, idx);
    k_edge<128, 256><<<BN_, 256, 0, stream>>>(x3, idx, w4T, g4f, b4f, x4);
    k_mha<256><<<N_, 256, 0, stream>>>(x4, a4wiT, bi4, a4woT, bo4);

    // head
    k_conv5<<<BN_ / 8, 256, 0, stream>>>(x1, x2, x3, x4, w5T, g5f, b5f, h5);
    k_pool<<<dim3(4, 8), 256, 0, stream>>>(h5, feat);
    k_fc1<<<8, 256, 0, stream>>>(feat, l1wT, g6f, b6f, f1);
    k_fc2<<<8, 256, 0, stream>>>(f1, l2wT, l2bf, g7f, b7f, f2);
    k_fc3<<<8, 64, 0, stream>>>(f2, l3wT, l3bf, d_out, flag);
}

// Round 7
// 1903.382 us; speedup vs baseline: 1.3980x; 1.1163x over previous
//
#include <hip/hip_runtime.h>
#include <hip/hip_bf16.h>

#define B_ 8
#define N_ 1024
#define K_ 20
#define BN_ (B_*N_)

// 1/sqrt(1+1e-5)  (eval-mode BN with running_var=1)
#define BN_SCALE 0.9999950000374997f

__device__ __forceinline__ float US2F(unsigned short u) {
    union { unsigned u; float f; } c; c.u = ((unsigned)u) << 16; return c.f;
}

// ---------------------------------------------------------------- dtype detect
__global__ void k_detect(const unsigned short* g1, const unsigned short* g2,
                         const unsigned short* g3, const unsigned short* g4,
                         const unsigned short* g5, const unsigned short* g6,
                         const unsigned short* g7, int* flag) {
    const unsigned short* gs[7] = {g1, g2, g3, g4, g5, g6, g7};
    int cnt = 0;
    for (int i = 0; i < 7; i++) {
        float v = US2F(gs[i][0]);
        if (v > 0.5f && v < 1.5f) cnt++;
    }
    *flag = (cnt >= 4) ? 1 : 0;   // 1 = bf16 inputs, 0 = fp32 inputs
}

// ---------------------------------------------------------------- prep:
// convert (+ transpose (O,I)->(I,O)) every weight/bias to fp32, either dtype.
struct TPar { const void* src; float* dst; int O, I, blk0; };
struct TList { TPar p[41]; };

__global__ __launch_bounds__(256) void k_prep(TList tl, int nent, const int* flag) {
    const int isbf = *flag;
    int blk = blockIdx.x;
    int wi = 0;
    for (int j = nent - 1; j >= 0; j--) { if (blk >= tl.p[j].blk0) { wi = j; break; } }
    const TPar p = tl.p[wi];
    int e = (blk - p.blk0) * 256 + threadIdx.x;
    int n = p.O * p.I;
    if (e >= n) return;
    int o = e / p.I, i = e - o * p.I;
    float v = isbf ? US2F(((const unsigned short*)p.src)[e])
                   : ((const float*)p.src)[e];
    p.dst[(size_t)i * p.O + o] = v;
}

// ---------------------------------------------------------------- norms
__global__ __launch_bounds__(256) void k_norms(const float* __restrict__ xf,
                                               float* __restrict__ xx, int C) {
    int i = blockIdx.x * 256 + threadIdx.x;
    if (i >= BN_) return;
    const float* p = xf + (size_t)i * C;
    float s = 0.f;
    for (int c = 0; c < C; c++) s += p[c] * p[c];
    xx[i] = s;
}

// ---------------------------------------------------------------- kNN top-20
// Block = 16 points (4 waves x 4 points), same batch. LDS-tiled distances
// (fixed the lane-varying-row global splits), ballot-based top-20.
template<int C>
__global__ __launch_bounds__(256, 3) void k_knn(const float* __restrict__ xf,
                                                const float* __restrict__ xx,
                                                int* __restrict__ idx) {
    const int t = threadIdx.x;
    const int w = t >> 6, lane = t & 63;
    const int pbase = blockIdx.x * 16;
    const int b = pbase >> 10, i0 = pbase & 1023;
    const float* xb  = xf + (size_t)b * N_ * C;
    const float* xxb = xx + (size_t)b * N_;

    __shared__ float xt[64][C + 1];
    __shared__ float ct[C][16];

    for (int u = t; u < 16 * C; u += 256) {
        int p = u / C, c = u - p * C;
        ct[c][p] = xb[(size_t)(i0 + p) * C + c];
    }

    float xxi[4];
    #pragma unroll
    for (int pp = 0; pp < 4; pp++) xxi[pp] = xxb[i0 + w * 4 + pp];

    float d[4][16];
    for (int q = 0; q < 16; q++) {
        __syncthreads();
        for (int u = t; u < 64 * C; u += 256) {
            int r = u / C, c = u - r * C;
            xt[r][c] = xb[(size_t)(q * 64 + r) * C + c];
        }
        __syncthreads();
        float a0 = 0.f, a1 = 0.f, a2 = 0.f, a3 = 0.f;
        #pragma unroll 4
        for (int c = 0; c < C; c++) {
            const float xjc = xt[lane][c];
            const float4 cv = *reinterpret_cast<const float4*>(&ct[c][w * 4]);
            a0 += xjc * cv.x; a1 += xjc * cv.y; a2 += xjc * cv.z; a3 += xjc * cv.w;
        }
        const float xxj = xxb[q * 64 + lane];
        d[0][q] = 2.f * a0 - xxi[0] - xxj;
        d[1][q] = 2.f * a1 - xxi[1] - xxj;
        d[2][q] = 2.f * a2 - xxi[2] - xxj;
        d[3][q] = 2.f * a3 - xxi[3] - xxj;
    }

    int myj[4] = {0, 0, 0, 0};
    #pragma unroll
    for (int pp = 0; pp < 4; pp++) {
        for (int kk = 0; kk < K_; kk++) {
            float v = d[pp][0];
            #pragma unroll
            for (int u = 1; u < 16; u++) v = fmaxf(v, d[pp][u]);
            #pragma unroll
            for (int s = 1; s < 64; s <<= 1) v = fmaxf(v, __shfl_xor(v, s, 64));
            int jw = -1;
            #pragma unroll
            for (int u = 0; u < 16; u++) {
                unsigned long long m = __ballot(d[pp][u] == v);
                if (jw < 0 && m != 0ULL) jw = u * 64 + (int)__ffsll((long long)m) - 1;
            }
            if (jw < 0) jw = 0;                    // unreachable guard
            if (lane == kk) myj[pp] = jw;
            const int wq = jw >> 6, wl = jw & 63;
            #pragma unroll
            for (int u = 0; u < 16; u++)
                if (u == wq && lane == wl) d[pp][u] = -3e38f;
        }
    }
    #pragma unroll
    for (int pp = 0; pp < 4; pp++)
        if (lane < K_) idx[(size_t)(pbase + w * 4 + pp) * K_ + lane] = myj[pp];
}

// ---------------------------------------------------------------- EdgeConv
template<int C, int CO>
__global__ __launch_bounds__(256) void k_edge(const float* __restrict__ xf,
                                              const int* __restrict__ idx,
                                              const float* __restrict__ wT,   // (2C, CO) fp32
                                              const float* __restrict__ g,
                                              const float* __restrict__ bb,
                                              float* __restrict__ out) {
    constexpr int TPC = CO / 4;            // threads along co (4 co each)
    constexpr int NG  = 256 / TPC;         // k-groups
    constexpr int KPT = (K_ + NG - 1) / NG;
    const int bi = blockIdx.x;
    const int b = bi >> 10, i = bi & 1023;
    const int t = threadIdx.x;
    __shared__ float ctr[C];
    __shared__ float df[K_][C];
    __shared__ float redm[NG][CO];
    const float* xb = xf + (size_t)b * N_ * C;
    for (int c = t; c < C; c += 256) ctr[c] = xb[(size_t)i * C + c];
    __syncthreads();
    for (int q = t; q < K_ * C; q += 256) {
        int kk = q / C, c = q - kk * C;
        int j = idx[bi * K_ + kk];
        df[kk][c] = xb[(size_t)j * C + c] - ctr[c];
    }
    __syncthreads();
    const int cog = (t % TPC) * 4;
    const int r   = t / TPC;
    float acc[KPT][4] = {};
    for (int c = 0; c < C; c++) {
        const float4 wv = *reinterpret_cast<const float4*>(&wT[(size_t)c * CO + cog]);
        #pragma unroll
        for (int gk = 0; gk < KPT; gk++) {
            int kk = r * KPT + gk;
            int kks = kk < K_ ? kk : K_ - 1;
            float dv = df[kks][c];
            acc[gk][0] += dv * wv.x; acc[gk][1] += dv * wv.y;
            acc[gk][2] += dv * wv.z; acc[gk][3] += dv * wv.w;
        }
    }
    float m[4] = {-3e38f, -3e38f, -3e38f, -3e38f};
    #pragma unroll
    for (int gk = 0; gk < KPT; gk++) {
        int kk = r * KPT + gk;
        if (kk < K_) {
            #pragma unroll
            for (int j = 0; j < 4; j++) m[j] = fmaxf(m[j], acc[gk][j]);
        }
    }
    #pragma unroll
    for (int j = 0; j < 4; j++) redm[r][cog + j] = m[j];
    __syncthreads();
    if (r == 0) {
        for (int rr = 1; rr < NG; rr++)
            #pragma unroll
            for (int j = 0; j < 4; j++) m[j] = fmaxf(m[j], redm[rr][cog + j]);
        float4 s2 = {0.f, 0.f, 0.f, 0.f};
        for (int c = 0; c < C; c++) {
            const float4 wv = *reinterpret_cast<const float4*>(&wT[(size_t)(C + c) * CO + cog]);
            float cv = ctr[c];
            s2.x += wv.x * cv; s2.y += wv.y * cv; s2.z += wv.z * cv; s2.w += wv.w * cv;
        }
        float sv[4] = {s2.x, s2.y, s2.z, s2.w};
        #pragma unroll
        for (int j = 0; j < 4; j++) {
            int co = cog + j;
            float val = m[j] + sv[j];
            float h = val * (g[co] * BN_SCALE) + bb[co];
            out[(size_t)bi * CO + co] = h >= 0.f ? h : 0.2f * h;
        }
    }
}

// ---------------------------------------------------------------- MHA as GEMMs
// k_gemm: C[8192][NC] = A[8192][KD] @ Bt[KD][NC] + bias; optional q-scale on
// cols < scale_cols; optional residual add. 64x64 tile, 4x4/thread, KT=32.
template<int KD, int NC>
__global__ __launch_bounds__(256) void k_gemm(const float* __restrict__ A,
                                              const float* __restrict__ Bt,
                                              const float* __restrict__ bias,
                                              const float* __restrict__ resid,
                                              float* __restrict__ Cout,
                                              int scale_cols, float qs) {
    const int t = threadIdx.x;
    const int rb = blockIdx.x * 64;
    const int cb = blockIdx.y * 64;
    __shared__ float As[64][33];
    __shared__ float Bs[32][68];
    float acc[4][4] = {};
    const int tm = (t >> 4) * 4, tn = (t & 15) * 4;
    for (int k0 = 0; k0 < KD; k0 += 32) {
        __syncthreads();
        #pragma unroll
        for (int u = t; u < 64 * 32; u += 256) {
            int m = u >> 5, k = u & 31;
            As[m][k] = A[(size_t)(rb + m) * KD + k0 + k];
        }
        #pragma unroll
        for (int u = t; u < 32 * 64; u += 256) {
            int k = u >> 6, c = u & 63;
            Bs[k][c] = Bt[(size_t)(k0 + k) * NC + cb + c];
        }
        __syncthreads();
        #pragma unroll
        for (int k = 0; k < 32; k++) {
            const float4 bv = *reinterpret_cast<const float4*>(&Bs[k][tn]);
            #pragma unroll
            for (int j = 0; j < 4; j++) {
                const float av = As[tm + j][k];
                acc[j][0] += av * bv.x; acc[j][1] += av * bv.y;
                acc[j][2] += av * bv.z; acc[j][3] += av * bv.w;
            }
        }
    }
    #pragma unroll
    for (int j = 0; j < 4; j++) {
        const int row = rb + tm + j;
        #pragma unroll
        for (int jj = 0; jj < 4; jj++) {
            const int col = cb + tn + jj;
            float v = acc[j][jj] + bias[col];
            if (col < scale_cols) v *= qs;
            if (resid) v += resid[(size_t)row * NC + col];
            Cout[(size_t)row * NC + col] = v;
        }
    }
}

// k_attn: per n, tiny 8x8 attention per head. qkv rows = (l*1024+n), cols 3E.
template<int E>
__global__ __launch_bounds__(256) void k_attn(const float* __restrict__ qkv,
                                              float* __restrict__ o) {
    constexpr int H = 4, D = E / H, L = 8;
    const int n = blockIdx.x;
    const int t = threadIdx.x;
    const int h = t >> 6, lane = t & 63;
    __shared__ float sq[L][3 * E];
    __shared__ float so[L][E];
    for (int u = t; u < L * 3 * E; u += 256) {
        int l = u / (3 * E), r = u - l * (3 * E);
        sq[l][r] = qkv[(size_t)(l * N_ + n) * (3 * E) + r];
    }
    __syncthreads();
    const int l = lane >> 3, m = lane & 7;
    float s = 0.f;
    #pragma unroll 8
    for (int dd = 0; dd < D; dd++)
        s += sq[l][h * D + dd] * sq[m][E + h * D + dd];
    float mx = s;
    #pragma unroll
    for (int st = 1; st < 8; st <<= 1) mx = fmaxf(mx, __shfl_xor(mx, st, 64));
    float e = expf(s - mx);
    float sum = e;
    #pragma unroll
    for (int st = 1; st < 8; st <<= 1) sum += __shfl_xor(sum, st, 64);
    const float p = e / sum;
    float pm[8];
    #pragma unroll
    for (int mm = 0; mm < 8; mm++) pm[mm] = __shfl(p, (lane & 56) | mm, 64);
    #pragma unroll
    for (int j = 0; j < D / 8; j++) {
        const int dd = m + 8 * j;
        float a = 0.f;
        #pragma unroll
        for (int mm = 0; mm < 8; mm++) a += pm[mm] * sq[mm][2 * E + h * D + dd];
        so[l][h * D + dd] = a;
    }
    __syncthreads();
    for (int u = t; u < L * E; u += 256) {
        int l2 = u / E, e2 = u - l2 * E;
        o[(size_t)(l2 * N_ + n) * E + e2] = so[l2][e2];
    }
}

// ---------------------------------------------------------------- conv5: cat(x1..x4) @ w5.T, BN, lrelu. 8 points/block.
__global__ __launch_bounds__(256) void k_conv5(const float* __restrict__ x1, const float* __restrict__ x2,
                                               const float* __restrict__ x3, const float* __restrict__ x4,
                                               const float* __restrict__ w5T,  // (512, 1024) fp32
                                               const float* __restrict__ g5,
                                               const float* __restrict__ b5,
                                               float* __restrict__ h5) {
    const int t = threadIdx.x;
    const int p0 = blockIdx.x * 8;
    __shared__ float cat[8][512];
    for (int u = t; u < 8 * 512; u += 256) {
        int p = u >> 9, c = u & 511;
        int pt = p0 + p;
        float v;
        if (c < 64)       v = x1[(size_t)pt * 64 + c];
        else if (c < 128) v = x2[(size_t)pt * 64 + (c - 64)];
        else if (c < 256) v = x3[(size_t)pt * 128 + (c - 128)];
        else              v = x4[(size_t)pt * 256 + (c - 256)];
        cat[p][c] = v;
    }
    __syncthreads();
    const int o = t * 4;
    float acc[8][4] = {};
    for (int c = 0; c < 512; c++) {
        const float4 wv = *reinterpret_cast<const float4*>(&w5T[(size_t)c * 1024 + o]);
        #pragma unroll
        for (int p = 0; p < 8; p++) {
            float cv = cat[p][c];
            acc[p][0] += cv * wv.x; acc[p][1] += cv * wv.y;
            acc[p][2] += cv * wv.z; acc[p][3] += cv * wv.w;
        }
    }
    #pragma unroll
    for (int p = 0; p < 8; p++) {
        #pragma unroll
        for (int j = 0; j < 4; j++) {
            int oo = o + j;
            float h = acc[p][j] * (g5[oo] * BN_SCALE) + b5[oo];
            h5[(size_t)(p0 + p) * 1024 + oo] = h >= 0.f ? h : 0.2f * h;
        }
    }
}

// ---------------------------------------------------------------- pool: max & mean over N per (b, channel)
__global__ __launch_bounds__(256) void k_pool(const float* __restrict__ h5, float* __restrict__ feat) {
    int c = blockIdx.x * 256 + threadIdx.x;   // 0..1023
    int b = blockIdx.y;
    float mx = -3e38f, sm = 0.f;
    for (int n = 0; n < N_; n++) {
        float v = h5[((size_t)b * N_ + n) * 1024 + c];
        mx = fmaxf(mx, v); sm += v;
    }
    feat[b * 2048 + c] = mx;
    feat[b * 2048 + 1024 + c] = sm * (1.f / 1024.f);
}

// ---------------------------------------------------------------- FC head
__global__ __launch_bounds__(256) void k_fc1(const float* __restrict__ feat, const float* __restrict__ l1wT,
                                             const float* __restrict__ g6, const float* __restrict__ b6,
                                             float* __restrict__ f1) {
    int b = blockIdx.x, t = threadIdx.x;
    __shared__ float fin[2048];
    for (int u = t; u < 2048; u += 256) fin[u] = feat[b * 2048 + u];
    __syncthreads();
    for (int o = t; o < 512; o += 256) {
        float acc = 0.f;
        for (int c = 0; c < 2048; c++) acc += fin[c] * l1wT[(size_t)c * 512 + o];
        float h = acc * (g6[o] * BN_SCALE) + b6[o];
        f1[b * 512 + o] = h >= 0.f ? h : 0.2f * h;
    }
}

__global__ __launch_bounds__(256) void k_fc2(const float* __restrict__ f1, const float* __restrict__ l2wT,
                                             const float* __restrict__ l2b,
                                             const float* __restrict__ g7, const float* __restrict__ b7,
                                             float* __restrict__ f2) {
    int b = blockIdx.x, t = threadIdx.x;
    __shared__ float fin[512];
    for (int u = t; u < 512; u += 256) fin[u] = f1[b * 512 + u];
    __syncthreads();
    if (t < 256) {
        int o = t;
        float acc = 0.f;
        for (int c = 0; c < 512; c++) acc += fin[c] * l2wT[(size_t)c * 256 + o];
        acc += l2b[o];
        float h = acc * (g7[o] * BN_SCALE) + b7[o];
        f2[b * 256 + o] = h >= 0.f ? h : 0.2f * h;
    }
}

__global__ __launch_bounds__(64) void k_fc3(const float* __restrict__ f2, const float* __restrict__ l3wT,
                                            const float* __restrict__ l3b,
                                            void* __restrict__ out, const int* __restrict__ flag) {
    int b = blockIdx.x, t = threadIdx.x;
    __shared__ float fin[256];
    for (int u = t; u < 256; u += 64) fin[u] = f2[b * 256 + u];
    __syncthreads();
    if (t < 40) {
        float acc = 0.f;
        for (int c = 0; c < 256; c++) acc += fin[c] * l3wT[(size_t)c * 40 + t];
        acc += l3b[t];
        if (*flag) ((__hip_bfloat16*)out)[b * 40 + t] = __float2bfloat16(acc);
        else       ((float*)out)[b * 40 + t] = acc;
    }
}

// ================================================================ host
extern "C" void kernel_launch(void* const* d_in, const int* in_sizes, int n_in,
                              void* d_out, int out_size, void* d_ws, size_t ws_size,
                              hipStream_t stream) {
    auto us = [&](int i) { return (const unsigned short*)d_in[i]; };

    float* ws = (float*)d_ws;
    size_t off = 0;
    auto A = [&](size_t n) { float* p = ws + off; off += (n + 3) & ~(size_t)3; return p; };
    float* xf0  = A((size_t)BN_ * 3);
    float* x1   = A((size_t)BN_ * 64);
    float* x2   = A((size_t)BN_ * 64);
    float* x3   = A((size_t)BN_ * 128);
    float* x4   = A((size_t)BN_ * 256);
    float* h5   = A((size_t)BN_ * 1024);
    float* feat = A(8 * 2048);
    float* f1   = A(8 * 512);
    float* f2   = A(8 * 256);
    float* xx   = A(BN_);
    int*   idx  = (int*)A((size_t)BN_ * K_);
    int*   flag = (int*)A(4);
    float* qkvw = A((size_t)BN_ * 768);   // mha qkv scratch (max E=256)
    float* ow   = A((size_t)BN_ * 256);   // mha attn-output scratch
    float* w1T   = A(6 * 64);
    float* w2T   = A(128 * 64);
    float* w3T   = A(128 * 128);
    float* w4T   = A(256 * 256);
    float* a1wiT = A(64 * 192);  float* a1woT = A(64 * 64);
    float* a2wiT = A(64 * 192);  float* a2woT = A(64 * 64);
    float* a3wiT = A(128 * 384); float* a3woT = A(128 * 128);
    float* a4wiT = A(256 * 768); float* a4woT = A(256 * 256);
    float* w5T   = A(512 * 1024);
    float* l1wT  = A(2048 * 512);
    float* l2wT  = A(512 * 256);
    float* l3wT  = A(256 * 40);
    // converted small vectors
    float* g1f = A(64);   float* b1f = A(64);
    float* g2f = A(64);   float* b2f = A(64);
    float* g3f = A(128);  float* b3f = A(128);
    float* g4f = A(256);  float* b4f = A(256);
    float* bi1 = A(192);  float* bo1 = A(64);
    float* bi2 = A(192);  float* bo2 = A(64);
    float* bi3 = A(384);  float* bo3 = A(128);
    float* bi4 = A(768);  float* bo4 = A(256);
    float* g5f = A(1024); float* b5f = A(1024);
    float* g6f = A(512);  float* b6f = A(512);
    float* l2bf = A(256);
    float* g7f = A(256);  float* b7f = A(256);
    float* l3bf = A(40);

    k_detect<<<1, 1, 0, stream>>>(us(2), us(5), us(8), us(11), us(30), us(33), us(37), flag);

    TList tl; int nb = 0; int k = 0;
    auto add = [&](int i, float* dst, int O, int I) {
        tl.p[k].src = d_in[i]; tl.p[k].dst = dst; tl.p[k].O = O; tl.p[k].I = I; tl.p[k].blk0 = nb;
        nb += (O * I + 255) / 256; k++;
    };
    add(0,  xf0,   BN_ * 3, 1);     // x convert (identity "transpose")
    add(1,  w1T,   64, 6);
    add(4,  w2T,   64, 128);
    add(7,  w3T,   128, 128);
    add(10, w4T,   256, 256);       // w4 is (256, 256): ci = 2*128
    add(13, a1wiT, 192, 64);
    add(15, a1woT, 64, 64);
    add(17, a2wiT, 192, 64);
    add(19, a2woT, 64, 64);
    add(21, a3wiT, 384, 128);
    add(23, a3woT, 128, 128);
    add(25, a4wiT, 768, 256);
    add(27, a4woT, 256, 256);
    add(29, w5T,   1024, 512);
    add(32, l1wT,  512, 2048);
    add(35, l2wT,  256, 512);
    add(39, l3wT,  40, 256);
    // vectors (identity convert)
    add(2,  g1f, 64, 1);   add(3,  b1f, 64, 1);
    add(5,  g2f, 64, 1);   add(6,  b2f, 64, 1);
    add(8,  g3f, 128, 1);  add(9,  b3f, 128, 1);
    add(11, g4f, 256, 1);  add(12, b4f, 256, 1);
    add(14, bi1, 192, 1);  add(16, bo1, 64, 1);
    add(18, bi2, 192, 1);  add(20, bo2, 64, 1);
    add(22, bi3, 384, 1);  add(24, bo3, 128, 1);
    add(26, bi4, 768, 1);  add(28, bo4, 256, 1);
    add(30, g5f, 1024, 1); add(31, b5f, 1024, 1);
    add(33, g6f, 512, 1);  add(34, b6f, 512, 1);
    add(36, l2bf, 256, 1);
    add(37, g7f, 256, 1);  add(38, b7f, 256, 1);
    add(40, l3bf, 40, 1);
    k_prep<<<nb, 256, 0, stream>>>(tl, k, flag);

    // MHA: qkv GEMM -> per-n attention -> out GEMM (+bias+residual)
    auto mha64 = [&](float* x, float* wiT, float* bi_, float* woT, float* bo_) {
        k_gemm<64, 192><<<dim3(128, 3), 256, 0, stream>>>(x, wiT, bi_, nullptr, qkvw, 64, 0.25f);
        k_attn<64><<<N_, 256, 0, stream>>>(qkvw, ow);
        k_gemm<64, 64><<<dim3(128, 1), 256, 0, stream>>>(ow, woT, bo_, x, x, 0, 1.f);
    };

    // layer 1  (C=3 -> 64)
    k_norms<<<BN_ / 256, 256, 0, stream>>>(xf0, xx, 3);
    k_knn<3><<<BN_ / 16, 256, 0, stream>>>(xf0, xx, idx);
    k_edge<3, 64><<<BN_, 256, 0, stream>>>(xf0, idx, w1T, g1f, b1f, x1);
    mha64(x1, a1wiT, bi1, a1woT, bo1);

    // layer 2  (C=64 -> 64)
    k_norms<<<BN_ / 256, 256, 0, stream>>>(x1, xx, 64);
    k_knn<64><<<BN_ / 16, 256, 0, stream>>>(x1, xx, idx);
    k_edge<64, 64><<<BN_, 256, 0, stream>>>(x1, idx, w2T, g2f, b2f, x2);
    mha64(x2, a2wiT, bi2, a2woT, bo2);

    // layer 3  (C=64 -> 128)
    k_norms<<<BN_ / 256, 256, 0, stream>>>(x2, xx, 64);
    k_knn<64><<<BN_ / 16, 256, 0, stream>>>(x2, xx, idx);
    k_edge<64, 128><<<BN_, 256, 0, stream>>>(x2, idx, w3T, g3f, b3f, x3);
    k_gemm<128, 384><<<dim3(128, 6), 256, 0, stream>>>(x3, a3wiT, bi3, nullptr, qkvw, 128, 0.17677669529663687f);
    k_attn<128><<<N_, 256, 0, stream>>>(qkvw, ow);
    k_gemm<128, 128><<<dim3(128, 2), 256, 0, stream>>>(ow, a3woT, bo3, x3, x3, 0, 1.f);

    // layer 4  (C=128 -> 256)
    k_norms<<<BN_ / 256, 256, 0, stream>>>(x3, xx, 128);
    k_knn<128><<<BN_ / 16, 256, 0, stream>>>(x3, xx, idx);
    k_edge<128, 256><<<BN_, 256, 0, stream>>>(x3, idx, w4T, g4f, b4f, x4);
    k_gemm<256, 768><<<dim3(128, 12), 256, 0, stream>>>(x4, a4wiT, bi4, nullptr, qkvw, 256, 0.125f);
    k_attn<256><<<N_, 256, 0, stream>>>(qkvw, ow);
    k_gemm<256, 256><<<dim3(128, 4), 256, 0, stream>>>(ow, a4woT, bo4, x4, x4, 0, 1.f);

    // head
    k_conv5<<<BN_ / 8, 256, 0, stream>>>(x1, x2, x3, x4, w5T, g5f, b5f, h5);
    k_pool<<<dim3(4, 8), 256, 0, stream>>>(h5, feat);
    k_fc1<<<8, 256, 0, stream>>>(feat, l1wT, g6f, b6f, f1);
    k_fc2<<<8, 256, 0, stream>>>(f1, l2wT, l2bf, g7f, b7f, f2);
    k_fc3<<<8, 64, 0, stream>>>(f2, l3wT, l3bf, d_out, flag);
}

// Round 8
// 1584.645 us; speedup vs baseline: 1.6791x; 1.2011x over previous
//
#include <hip/hip_runtime.h>
#include <hip/hip_bf16.h>

#define B_ 8
#define N_ 1024
#define K_ 20
#define BN_ (B_*N_)

// 1/sqrt(1+1e-5)  (eval-mode BN with running_var=1)
#define BN_SCALE 0.9999950000374997f

__device__ __forceinline__ float US2F(unsigned short u) {
    union { unsigned u; float f; } c; c.u = ((unsigned)u) << 16; return c.f;
}

// ---------------------------------------------------------------- dtype detect
__global__ void k_detect(const unsigned short* g1, const unsigned short* g2,
                         const unsigned short* g3, const unsigned short* g4,
                         const unsigned short* g5, const unsigned short* g6,
                         const unsigned short* g7, int* flag) {
    const unsigned short* gs[7] = {g1, g2, g3, g4, g5, g6, g7};
    int cnt = 0;
    for (int i = 0; i < 7; i++) {
        float v = US2F(gs[i][0]);
        if (v > 0.5f && v < 1.5f) cnt++;
    }
    *flag = (cnt >= 4) ? 1 : 0;   // 1 = bf16 inputs, 0 = fp32 inputs
}

// ---------------------------------------------------------------- prep:
// convert (+ transpose (O,I)->(I,O)) every weight/bias to fp32, either dtype.
struct TPar { const void* src; float* dst; int O, I, blk0; };
struct TList { TPar p[41]; };

__global__ __launch_bounds__(256) void k_prep(TList tl, int nent, const int* flag) {
    const int isbf = *flag;
    int blk = blockIdx.x;
    int wi = 0;
    for (int j = nent - 1; j >= 0; j--) { if (blk >= tl.p[j].blk0) { wi = j; break; } }
    const TPar p = tl.p[wi];
    int e = (blk - p.blk0) * 256 + threadIdx.x;
    int n = p.O * p.I;
    if (e >= n) return;
    int o = e / p.I, i = e - o * p.I;
    float v = isbf ? US2F(((const unsigned short*)p.src)[e])
                   : ((const float*)p.src)[e];
    p.dst[(size_t)i * p.O + o] = v;
}

// ---------------------------------------------------------------- norms
__global__ __launch_bounds__(256) void k_norms(const float* __restrict__ xf,
                                               float* __restrict__ xx, int C) {
    int i = blockIdx.x * 256 + threadIdx.x;
    if (i >= BN_) return;
    const float* p = xf + (size_t)i * C;
    float s = 0.f;
    for (int c = 0; c < C; c++) s += p[c] * p[c];
    xx[i] = s;
}

// ---------------------------------------------------------------- kNN top-20
// Block = 16 points (4 waves x 4 points), same batch. LDS-tiled distances,
// ballot-based top-20.
template<int C>
__global__ __launch_bounds__(256, 3) void k_knn(const float* __restrict__ xf,
                                                const float* __restrict__ xx,
                                                int* __restrict__ idx) {
    const int t = threadIdx.x;
    const int w = t >> 6, lane = t & 63;
    const int pbase = blockIdx.x * 16;
    const int b = pbase >> 10, i0 = pbase & 1023;
    const float* xb  = xf + (size_t)b * N_ * C;
    const float* xxb = xx + (size_t)b * N_;

    __shared__ float xt[64][C + 1];
    __shared__ float ct[C][16];

    for (int u = t; u < 16 * C; u += 256) {
        int p = u / C, c = u - p * C;
        ct[c][p] = xb[(size_t)(i0 + p) * C + c];
    }

    float xxi[4];
    #pragma unroll
    for (int pp = 0; pp < 4; pp++) xxi[pp] = xxb[i0 + w * 4 + pp];

    float d[4][16];
    for (int q = 0; q < 16; q++) {
        __syncthreads();
        for (int u = t; u < 64 * C; u += 256) {
            int r = u / C, c = u - r * C;
            xt[r][c] = xb[(size_t)(q * 64 + r) * C + c];
        }
        __syncthreads();
        float a0 = 0.f, a1 = 0.f, a2 = 0.f, a3 = 0.f;
        #pragma unroll 4
        for (int c = 0; c < C; c++) {
            const float xjc = xt[lane][c];
            const float4 cv = *reinterpret_cast<const float4*>(&ct[c][w * 4]);
            a0 += xjc * cv.x; a1 += xjc * cv.y; a2 += xjc * cv.z; a3 += xjc * cv.w;
        }
        const float xxj = xxb[q * 64 + lane];
        d[0][q] = 2.f * a0 - xxi[0] - xxj;
        d[1][q] = 2.f * a1 - xxi[1] - xxj;
        d[2][q] = 2.f * a2 - xxi[2] - xxj;
        d[3][q] = 2.f * a3 - xxi[3] - xxj;
    }

    int myj[4] = {0, 0, 0, 0};
    #pragma unroll
    for (int pp = 0; pp < 4; pp++) {
        for (int kk = 0; kk < K_; kk++) {
            float v = d[pp][0];
            #pragma unroll
            for (int u = 1; u < 16; u++) v = fmaxf(v, d[pp][u]);
            #pragma unroll
            for (int s = 1; s < 64; s <<= 1) v = fmaxf(v, __shfl_xor(v, s, 64));
            int jw = -1;
            #pragma unroll
            for (int u = 0; u < 16; u++) {
                unsigned long long m = __ballot(d[pp][u] == v);
                if (jw < 0 && m != 0ULL) jw = u * 64 + (int)__ffsll((long long)m) - 1;
            }
            if (jw < 0) jw = 0;                    // unreachable guard
            if (lane == kk) myj[pp] = jw;
            const int wq = jw >> 6, wl = jw & 63;
            #pragma unroll
            for (int u = 0; u < 16; u++)
                if (u == wq && lane == wl) d[pp][u] = -3e38f;
        }
    }
    #pragma unroll
    for (int pp = 0; pp < 4; pp++)
        if (lane < K_) idx[(size_t)(pbase + w * 4 + pp) * K_ + lane] = myj[pp];
}

// ---------------------------------------------------------------- GEMM
// C[8192][NC] = A[8192][KD] @ Bt[KD][NC] (+bias) ; optional q-scale on cols <
// scale_cols; optional residual. 64x64 tile, 4x4/thread, KT=32, K-remainder
// guarded at compile time (enables KD=3).
template<int KD, int NC>
__global__ __launch_bounds__(256) void k_gemm(const float* __restrict__ A,
                                              const float* __restrict__ Bt,
                                              const float* __restrict__ bias,
                                              const float* __restrict__ resid,
                                              float* __restrict__ Cout,
                                              int scale_cols, float qs) {
    const int t = threadIdx.x;
    const int rb = blockIdx.x * 64;
    const int cb = blockIdx.y * 64;
    __shared__ float As[64][33];
    __shared__ float Bs[32][68];
    float acc[4][4] = {};
    const int tm = (t >> 4) * 4, tn = (t & 15) * 4;
    for (int k0 = 0; k0 < KD; k0 += 32) {
        __syncthreads();
        #pragma unroll
        for (int u = t; u < 64 * 32; u += 256) {
            int m = u >> 5, k = u & 31;
            float av;
            if constexpr (KD % 32 == 0) av = A[(size_t)(rb + m) * KD + k0 + k];
            else av = (k0 + k < KD) ? A[(size_t)(rb + m) * KD + k0 + k] : 0.f;
            As[m][k] = av;
        }
        #pragma unroll
        for (int u = t; u < 32 * 64; u += 256) {
            int k = u >> 6, c = u & 63;
            float bvv;
            if constexpr (KD % 32 == 0) bvv = Bt[(size_t)(k0 + k) * NC + cb + c];
            else bvv = (k0 + k < KD) ? Bt[(size_t)(k0 + k) * NC + cb + c] : 0.f;
            Bs[k][c] = bvv;
        }
        __syncthreads();
        #pragma unroll
        for (int k = 0; k < 32; k++) {
            const float4 bv = *reinterpret_cast<const float4*>(&Bs[k][tn]);
            #pragma unroll
            for (int j = 0; j < 4; j++) {
                const float av = As[tm + j][k];
                acc[j][0] += av * bv.x; acc[j][1] += av * bv.y;
                acc[j][2] += av * bv.z; acc[j][3] += av * bv.w;
            }
        }
    }
    #pragma unroll
    for (int j = 0; j < 4; j++) {
        const int row = rb + tm + j;
        #pragma unroll
        for (int jj = 0; jj < 4; jj++) {
            const int col = cb + tn + jj;
            float v = acc[j][jj] + (bias ? bias[col] : 0.f);
            if (col < scale_cols) v *= qs;
            if (resid) v += resid[(size_t)row * NC + col];
            Cout[(size_t)row * NC + col] = v;
        }
    }
}

// ---------------------------------------------------------------- EdgeConv epilogue
// out[i] = lrelu(bn( max_k y[j_k] - y[i] + z[i] ))   (y=X@wn, z=X@wc)
template<int CO>
__global__ __launch_bounds__(256) void k_edgemax(const float* __restrict__ y,
                                                 const float* __restrict__ z,
                                                 const int* __restrict__ idx,
                                                 const float* __restrict__ g,
                                                 const float* __restrict__ bb,
                                                 float* __restrict__ out) {
    constexpr int TPP = CO / 4;          // threads per point
    constexpr int PPB = 256 / TPP;       // points per block (same batch: 1024%PPB==0)
    const int t = threadIdx.x;
    const int p = t / TPP;
    const int cw = (t % TPP) * 4;
    const int i0 = blockIdx.x * PPB;
    const int bbase = (i0 >> 10) << 10;
    __shared__ int sidx[PPB][K_];
    for (int u = t; u < PPB * K_; u += 256) {
        int pp = u / K_, kk = u - pp * K_;
        sidx[pp][kk] = idx[(size_t)(i0 + pp) * K_ + kk];
    }
    __syncthreads();
    const int ig = i0 + p;
    float4 m = {-3e38f, -3e38f, -3e38f, -3e38f};
    #pragma unroll 4
    for (int k = 0; k < K_; k++) {
        const int jg = bbase + sidx[p][k];
        const float4 yv = *reinterpret_cast<const float4*>(&y[(size_t)jg * CO + cw]);
        m.x = fmaxf(m.x, yv.x); m.y = fmaxf(m.y, yv.y);
        m.z = fmaxf(m.z, yv.z); m.w = fmaxf(m.w, yv.w);
    }
    const float4 yi = *reinterpret_cast<const float4*>(&y[(size_t)ig * CO + cw]);
    const float4 zi = *reinterpret_cast<const float4*>(&z[(size_t)ig * CO + cw]);
    const float4 gv = *reinterpret_cast<const float4*>(&g[cw]);
    const float4 bv = *reinterpret_cast<const float4*>(&bb[cw]);
    float vals[4] = {m.x - yi.x + zi.x, m.y - yi.y + zi.y,
                     m.z - yi.z + zi.z, m.w - yi.w + zi.w};
    float gs[4] = {gv.x, gv.y, gv.z, gv.w};
    float bs[4] = {bv.x, bv.y, bv.z, bv.w};
    float4 o;
    float* op = &o.x;
    #pragma unroll
    for (int j = 0; j < 4; j++) {
        float h = vals[j] * (gs[j] * BN_SCALE) + bs[j];
        op[j] = h >= 0.f ? h : 0.2f * h;
    }
    *reinterpret_cast<float4*>(&out[(size_t)ig * CO + cw]) = o;
}

// ---------------------------------------------------------------- attention (per n, 8x8 per head)
template<int E>
__global__ __launch_bounds__(256) void k_attn(const float* __restrict__ qkv,
                                              float* __restrict__ o) {
    constexpr int H = 4, D = E / H, L = 8;
    const int n = blockIdx.x;
    const int t = threadIdx.x;
    const int h = t >> 6, lane = t & 63;
    __shared__ float sq[L][3 * E];
    __shared__ float so[L][E];
    for (int u = t; u < L * 3 * E; u += 256) {
        int l = u / (3 * E), r = u - l * (3 * E);
        sq[l][r] = qkv[(size_t)(l * N_ + n) * (3 * E) + r];
    }
    __syncthreads();
    const int l = lane >> 3, m = lane & 7;
    float s = 0.f;
    #pragma unroll 8
    for (int dd = 0; dd < D; dd++)
        s += sq[l][h * D + dd] * sq[m][E + h * D + dd];
    float mx = s;
    #pragma unroll
    for (int st = 1; st < 8; st <<= 1) mx = fmaxf(mx, __shfl_xor(mx, st, 64));
    float e = expf(s - mx);
    float sum = e;
    #pragma unroll
    for (int st = 1; st < 8; st <<= 1) sum += __shfl_xor(sum, st, 64);
    const float p = e / sum;
    float pm[8];
    #pragma unroll
    for (int mm = 0; mm < 8; mm++) pm[mm] = __shfl(p, (lane & 56) | mm, 64);
    #pragma unroll
    for (int j = 0; j < D / 8; j++) {
        const int dd = m + 8 * j;
        float a = 0.f;
        #pragma unroll
        for (int mm = 0; mm < 8; mm++) a += pm[mm] * sq[mm][2 * E + h * D + dd];
        so[l][h * D + dd] = a;
    }
    __syncthreads();
    for (int u = t; u < L * E; u += 256) {
        int l2 = u / E, e2 = u - l2 * E;
        o[(size_t)(l2 * N_ + n) * E + e2] = so[l2][e2];
    }
}

// ---------------------------------------------------------------- conv5: cat(x1..x4) @ w5.T, BN, lrelu. 8 points/block.
__global__ __launch_bounds__(256) void k_conv5(const float* __restrict__ x1, const float* __restrict__ x2,
                                               const float* __restrict__ x3, const float* __restrict__ x4,
                                               const float* __restrict__ w5T,  // (512, 1024) fp32
                                               const float* __restrict__ g5,
                                               const float* __restrict__ b5,
                                               float* __restrict__ h5) {
    const int t = threadIdx.x;
    const int p0 = blockIdx.x * 8;
    __shared__ float cat[8][512];
    for (int u = t; u < 8 * 512; u += 256) {
        int p = u >> 9, c = u & 511;
        int pt = p0 + p;
        float v;
        if (c < 64)       v = x1[(size_t)pt * 64 + c];
        else if (c < 128) v = x2[(size_t)pt * 64 + (c - 64)];
        else if (c < 256) v = x3[(size_t)pt * 128 + (c - 128)];
        else              v = x4[(size_t)pt * 256 + (c - 256)];
        cat[p][c] = v;
    }
    __syncthreads();
    const int o = t * 4;
    float acc[8][4] = {};
    for (int c = 0; c < 512; c++) {
        const float4 wv = *reinterpret_cast<const float4*>(&w5T[(size_t)c * 1024 + o]);
        #pragma unroll
        for (int p = 0; p < 8; p++) {
            float cv = cat[p][c];
            acc[p][0] += cv * wv.x; acc[p][1] += cv * wv.y;
            acc[p][2] += cv * wv.z; acc[p][3] += cv * wv.w;
        }
    }
    #pragma unroll
    for (int p = 0; p < 8; p++) {
        #pragma unroll
        for (int j = 0; j < 4; j++) {
            int oo = o + j;
            float h = acc[p][j] * (g5[oo] * BN_SCALE) + b5[oo];
            h5[(size_t)(p0 + p) * 1024 + oo] = h >= 0.f ? h : 0.2f * h;
        }
    }
}

// ---------------------------------------------------------------- pool: max & mean over N per (b, channel)
__global__ __launch_bounds__(256) void k_pool(const float* __restrict__ h5, float* __restrict__ feat) {
    int c = blockIdx.x * 256 + threadIdx.x;   // 0..1023
    int b = blockIdx.y;
    float mx = -3e38f, sm = 0.f;
    for (int n = 0; n < N_; n++) {
        float v = h5[((size_t)b * N_ + n) * 1024 + c];
        mx = fmaxf(mx, v); sm += v;
    }
    feat[b * 2048 + c] = mx;
    feat[b * 2048 + 1024 + c] = sm * (1.f / 1024.f);
}

// ---------------------------------------------------------------- FC head
__global__ __launch_bounds__(256) void k_fc1(const float* __restrict__ feat, const float* __restrict__ l1wT,
                                             const float* __restrict__ g6, const float* __restrict__ b6,
                                             float* __restrict__ f1) {
    int b = blockIdx.x, t = threadIdx.x;
    __shared__ float fin[2048];
    for (int u = t; u < 2048; u += 256) fin[u] = feat[b * 2048 + u];
    __syncthreads();
    for (int o = t; o < 512; o += 256) {
        float acc = 0.f;
        for (int c = 0; c < 2048; c++) acc += fin[c] * l1wT[(size_t)c * 512 + o];
        float h = acc * (g6[o] * BN_SCALE) + b6[o];
        f1[b * 512 + o] = h >= 0.f ? h : 0.2f * h;
    }
}

__global__ __launch_bounds__(256) void k_fc2(const float* __restrict__ f1, const float* __restrict__ l2wT,
                                             const float* __restrict__ l2b,
                                             const float* __restrict__ g7, const float* __restrict__ b7,
                                             float* __restrict__ f2) {
    int b = blockIdx.x, t = threadIdx.x;
    __shared__ float fin[512];
    for (int u = t; u < 512; u += 256) fin[u] = f1[b * 512 + u];
    __syncthreads();
    if (t < 256) {
        int o = t;
        float acc = 0.f;
        for (int c = 0; c < 512; c++) acc += fin[c] * l2wT[(size_t)c * 256 + o];
        acc += l2b[o];
        float h = acc * (g7[o] * BN_SCALE) + b7[o];
        f2[b * 256 + o] = h >= 0.f ? h : 0.2f * h;
    }
}

__global__ __launch_bounds__(64) void k_fc3(const float* __restrict__ f2, const float* __restrict__ l3wT,
                                            const float* __restrict__ l3b,
                                            void* __restrict__ out, const int* __restrict__ flag) {
    int b = blockIdx.x, t = threadIdx.x;
    __shared__ float fin[256];
    for (int u = t; u < 256; u += 64) fin[u] = f2[b * 256 + u];
    __syncthreads();
    if (t < 40) {
        float acc = 0.f;
        for (int c = 0; c < 256; c++) acc += fin[c] * l3wT[(size_t)c * 40 + t];
        acc += l3b[t];
        if (*flag) ((__hip_bfloat16*)out)[b * 40 + t] = __float2bfloat16(acc);
        else       ((float*)out)[b * 40 + t] = acc;
    }
}

// ================================================================ host
extern "C" void kernel_launch(void* const* d_in, const int* in_sizes, int n_in,
                              void* d_out, int out_size, void* d_ws, size_t ws_size,
                              hipStream_t stream) {
    auto us = [&](int i) { return (const unsigned short*)d_in[i]; };

    float* ws = (float*)d_ws;
    size_t off = 0;
    auto A = [&](size_t n) { float* p = ws + off; off += (n + 3) & ~(size_t)3; return p; };
    float* xf0  = A((size_t)BN_ * 3);
    float* x1   = A((size_t)BN_ * 64);
    float* x2   = A((size_t)BN_ * 64);
    float* x3   = A((size_t)BN_ * 128);
    float* x4   = A((size_t)BN_ * 256);
    float* h5   = A((size_t)BN_ * 1024);
    float* feat = A(8 * 2048);
    float* f1   = A(8 * 512);
    float* f2   = A(8 * 256);
    float* xx   = A(BN_);
    int*   idx  = (int*)A((size_t)BN_ * K_);
    int*   flag = (int*)A(4);
    float* qkvw = A((size_t)BN_ * 768);   // qkv scratch / edge y
    float* ow   = A((size_t)BN_ * 256);   // attn-out scratch / edge z
    float* w1T   = A(6 * 64);
    float* w2T   = A(128 * 64);
    float* w3T   = A(128 * 128);
    float* w4T   = A(256 * 256);
    float* a1wiT = A(64 * 192);  float* a1woT = A(64 * 64);
    float* a2wiT = A(64 * 192);  float* a2woT = A(64 * 64);
    float* a3wiT = A(128 * 384); float* a3woT = A(128 * 128);
    float* a4wiT = A(256 * 768); float* a4woT = A(256 * 256);
    float* w5T   = A(512 * 1024);
    float* l1wT  = A(2048 * 512);
    float* l2wT  = A(512 * 256);
    float* l3wT  = A(256 * 40);
    // converted small vectors
    float* g1f = A(64);   float* b1f = A(64);
    float* g2f = A(64);   float* b2f = A(64);
    float* g3f = A(128);  float* b3f = A(128);
    float* g4f = A(256);  float* b4f = A(256);
    float* bi1 = A(192);  float* bo1 = A(64);
    float* bi2 = A(192);  float* bo2 = A(64);
    float* bi3 = A(384);  float* bo3 = A(128);
    float* bi4 = A(768);  float* bo4 = A(256);
    float* g5f = A(1024); float* b5f = A(1024);
    float* g6f = A(512);  float* b6f = A(512);
    float* l2bf = A(256);
    float* g7f = A(256);  float* b7f = A(256);
    float* l3bf = A(40);

    k_detect<<<1, 1, 0, stream>>>(us(2), us(5), us(8), us(11), us(30), us(33), us(37), flag);

    TList tl; int nb = 0; int k = 0;
    auto add = [&](int i, float* dst, int O, int I) {
        tl.p[k].src = d_in[i]; tl.p[k].dst = dst; tl.p[k].O = O; tl.p[k].I = I; tl.p[k].blk0 = nb;
        nb += (O * I + 255) / 256; k++;
    };
    add(0,  xf0,   BN_ * 3, 1);     // x convert (identity "transpose")
    add(1,  w1T,   64, 6);
    add(4,  w2T,   64, 128);
    add(7,  w3T,   128, 128);
    add(10, w4T,   256, 256);       // w4 is (256, 256): ci = 2*128
    add(13, a1wiT, 192, 64);
    add(15, a1woT, 64, 64);
    add(17, a2wiT, 192, 64);
    add(19, a2woT, 64, 64);
    add(21, a3wiT, 384, 128);
    add(23, a3woT, 128, 128);
    add(25, a4wiT, 768, 256);
    add(27, a4woT, 256, 256);
    add(29, w5T,   1024, 512);
    add(32, l1wT,  512, 2048);
    add(35, l2wT,  256, 512);
    add(39, l3wT,  40, 256);
    // vectors (identity convert)
    add(2,  g1f, 64, 1);   add(3,  b1f, 64, 1);
    add(5,  g2f, 64, 1);   add(6,  b2f, 64, 1);
    add(8,  g3f, 128, 1);  add(9,  b3f, 128, 1);
    add(11, g4f, 256, 1);  add(12, b4f, 256, 1);
    add(14, bi1, 192, 1);  add(16, bo1, 64, 1);
    add(18, bi2, 192, 1);  add(20, bo2, 64, 1);
    add(22, bi3, 384, 1);  add(24, bo3, 128, 1);
    add(26, bi4, 768, 1);  add(28, bo4, 256, 1);
    add(30, g5f, 1024, 1); add(31, b5f, 1024, 1);
    add(33, g6f, 512, 1);  add(34, b6f, 512, 1);
    add(36, l2bf, 256, 1);
    add(37, g7f, 256, 1);  add(38, b7f, 256, 1);
    add(40, l3bf, 40, 1);
    k_prep<<<nb, 256, 0, stream>>>(tl, k, flag);

    float* ye = qkvw;   // edge y scratch
    float* ze = ow;     // edge z scratch

    // layer 1  (C=3 -> 64)
    k_norms<<<BN_ / 256, 256, 0, stream>>>(xf0, xx, 3);
    k_knn<3><<<BN_ / 16, 256, 0, stream>>>(xf0, xx, idx);
    k_gemm<3, 64><<<dim3(128, 1), 256, 0, stream>>>(xf0, w1T, nullptr, nullptr, ye, 0, 1.f);
    k_gemm<3, 64><<<dim3(128, 1), 256, 0, stream>>>(xf0, w1T + 3 * 64, nullptr, nullptr, ze, 0, 1.f);
    k_edgemax<64><<<BN_ / 16, 256, 0, stream>>>(ye, ze, idx, g1f, b1f, x1);
    k_gemm<64, 192><<<dim3(128, 3), 256, 0, stream>>>(x1, a1wiT, bi1, nullptr, qkvw, 64, 0.25f);
    k_attn<64><<<N_, 256, 0, stream>>>(qkvw, ow);
    k_gemm<64, 64><<<dim3(128, 1), 256, 0, stream>>>(ow, a1woT, bo1, x1, x1, 0, 1.f);

    // layer 2  (C=64 -> 64)
    k_norms<<<BN_ / 256, 256, 0, stream>>>(x1, xx, 64);
    k_knn<64><<<BN_ / 16, 256, 0, stream>>>(x1, xx, idx);
    k_gemm<64, 64><<<dim3(128, 1), 256, 0, stream>>>(x1, w2T, nullptr, nullptr, ye, 0, 1.f);
    k_gemm<64, 64><<<dim3(128, 1), 256, 0, stream>>>(x1, w2T + 64 * 64, nullptr, nullptr, ze, 0, 1.f);
    k_edgemax<64><<<BN_ / 16, 256, 0, stream>>>(ye, ze, idx, g2f, b2f, x2);
    k_gemm<64, 192><<<dim3(128, 3), 256, 0, stream>>>(x2, a2wiT, bi2, nullptr, qkvw, 64, 0.25f);
    k_attn<64><<<N_, 256, 0, stream>>>(qkvw, ow);
    k_gemm<64, 64><<<dim3(128, 1), 256, 0, stream>>>(ow, a2woT, bo2, x2, x2, 0, 1.f);

    // layer 3  (C=64 -> 128)
    k_norms<<<BN_ / 256, 256, 0, stream>>>(x2, xx, 64);
    k_knn<64><<<BN_ / 16, 256, 0, stream>>>(x2, xx, idx);
    k_gemm<64, 128><<<dim3(128, 2), 256, 0, stream>>>(x2, w3T, nullptr, nullptr, ye, 0, 1.f);
    k_gemm<64, 128><<<dim3(128, 2), 256, 0, stream>>>(x2, w3T + 64 * 128, nullptr, nullptr, ze, 0, 1.f);
    k_edgemax<128><<<BN_ / 8, 256, 0, stream>>>(ye, ze, idx, g3f, b3f, x3);
    k_gemm<128, 384><<<dim3(128, 6), 256, 0, stream>>>(x3, a3wiT, bi3, nullptr, qkvw, 128, 0.17677669529663687f);
    k_attn<128><<<N_, 256, 0, stream>>>(qkvw, ow);
    k_gemm<128, 128><<<dim3(128, 2), 256, 0, stream>>>(ow, a3woT, bo3, x3, x3, 0, 1.f);

    // layer 4  (C=128 -> 256)
    k_norms<<<BN_ / 256, 256, 0, stream>>>(x3, xx, 128);
    k_knn<128><<<BN_ / 16, 256, 0, stream>>>(x3, xx, idx);
    k_gemm<128, 256><<<dim3(128, 4), 256, 0, stream>>>(x3, w4T, nullptr, nullptr, ye, 0, 1.f);
    k_gemm<128, 256><<<dim3(128, 4), 256, 0, stream>>>(x3, w4T + 128 * 256, nullptr, nullptr, ze, 0, 1.f);
    k_edgemax<256><<<BN_ / 4, 256, 0, stream>>>(ye, ze, idx, g4f, b4f, x4);
    k_gemm<256, 768><<<dim3(128, 12), 256, 0, stream>>>(x4, a4wiT, bi4, nullptr, qkvw, 256, 0.125f);
    k_attn<256><<<N_, 256, 0, stream>>>(qkvw, ow);
    k_gemm<256, 256><<<dim3(128, 4), 256, 0, stream>>>(ow, a4woT, bo4, x4, x4, 0, 1.f);

    // head
    k_conv5<<<BN_ / 8, 256, 0, stream>>>(x1, x2, x3, x4, w5T, g5f, b5f, h5);
    k_pool<<<dim3(4, 8), 256, 0, stream>>>(h5, feat);
    k_fc1<<<8, 256, 0, stream>>>(feat, l1wT, g6f, b6f, f1);
    k_fc2<<<8, 256, 0, stream>>>(f1, l2wT, l2bf, g7f, b7f, f2);
    k_fc3<<<8, 64, 0, stream>>>(f2, l3wT, l3bf, d_out, flag);
}

// Round 9
// 1380.918 us; speedup vs baseline: 1.9269x; 1.1475x over previous
//
#include <hip/hip_runtime.h>
#include <hip/hip_bf16.h>

#define B_ 8
#define N_ 1024
#define K_ 20
#define BN_ (B_*N_)

// 1/sqrt(1+1e-5)  (eval-mode BN with running_var=1)
#define BN_SCALE 0.9999950000374997f

__device__ __forceinline__ float US2F(unsigned short u) {
    union { unsigned u; float f; } c; c.u = ((unsigned)u) << 16; return c.f;
}

// ---------------------------------------------------------------- dtype detect
__global__ void k_detect(const unsigned short* g1, const unsigned short* g2,
                         const unsigned short* g3, const unsigned short* g4,
                         const unsigned short* g5, const unsigned short* g6,
                         const unsigned short* g7, int* flag) {
    const unsigned short* gs[7] = {g1, g2, g3, g4, g5, g6, g7};
    int cnt = 0;
    for (int i = 0; i < 7; i++) {
        float v = US2F(gs[i][0]);
        if (v > 0.5f && v < 1.5f) cnt++;
    }
    *flag = (cnt >= 4) ? 1 : 0;   // 1 = bf16 inputs, 0 = fp32 inputs
}

// ---------------------------------------------------------------- prep:
// convert (+ transpose (O,I)->(I,O)) every weight/bias to fp32, either dtype.
struct TPar { const void* src; float* dst; int O, I, blk0; };
struct TList { TPar p[41]; };

__global__ __launch_bounds__(256) void k_prep(TList tl, int nent, const int* flag) {
    const int isbf = *flag;
    int blk = blockIdx.x;
    int wi = 0;
    for (int j = nent - 1; j >= 0; j--) { if (blk >= tl.p[j].blk0) { wi = j; break; } }
    const TPar p = tl.p[wi];
    int e = (blk - p.blk0) * 256 + threadIdx.x;
    int n = p.O * p.I;
    if (e >= n) return;
    int o = e / p.I, i = e - o * p.I;
    float v = isbf ? US2F(((const unsigned short*)p.src)[e])
                   : ((const float*)p.src)[e];
    p.dst[(size_t)i * p.O + o] = v;
}

// ---------------------------------------------------------------- norms
__global__ __launch_bounds__(256) void k_norms(const float* __restrict__ xf,
                                               float* __restrict__ xx, int C) {
    int i = blockIdx.x * 256 + threadIdx.x;
    if (i >= BN_) return;
    const float* p = xf + (size_t)i * C;
    float s = 0.f;
    for (int c = 0; c < C; c++) s += p[c] * p[c];
    xx[i] = s;
}

// ---------------------------------------------------------------- kNN phase 1:
// pd[b] = 2 * X_b @ X_b^T  (1024x1024 per batch), 64x64 tiles, 4x4/thread.
// The -xx_i row term is argmax-invariant and dropped; -xx_j applied in k_sel.
template<int C>
__global__ __launch_bounds__(256) void k_pd(const float* __restrict__ xf,
                                            float* __restrict__ pd) {
    const int b = blockIdx.z;
    const int rb = blockIdx.x * 64, cb = blockIdx.y * 64;
    const float* xb = xf + (size_t)b * N_ * C;
    const int t = threadIdx.x;
    __shared__ float As[64][33];
    __shared__ float Bs[32][65];
    float acc[4][4] = {};
    const int tm = (t >> 4) * 4, tn = (t & 15) * 4;
    for (int k0 = 0; k0 < C; k0 += 32) {
        __syncthreads();
        #pragma unroll
        for (int u = t; u < 64 * 32; u += 256) {
            int m = u >> 5, k = u & 31;
            float v;
            if constexpr (C % 32 == 0) v = xb[(size_t)(rb + m) * C + k0 + k];
            else v = (k0 + k < C) ? xb[(size_t)(rb + m) * C + k0 + k] : 0.f;
            As[m][k] = v;
        }
        #pragma unroll
        for (int u = t; u < 64 * 32; u += 256) {
            int j = u >> 5, k = u & 31;
            float v;
            if constexpr (C % 32 == 0) v = xb[(size_t)(cb + j) * C + k0 + k];
            else v = (k0 + k < C) ? xb[(size_t)(cb + j) * C + k0 + k] : 0.f;
            Bs[k][j] = v;
        }
        __syncthreads();
        #pragma unroll
        for (int k = 0; k < 32; k++) {
            const float4 bv = *reinterpret_cast<const float4*>(&Bs[k][tn]);
            #pragma unroll
            for (int j = 0; j < 4; j++) {
                const float av = As[tm + j][k];
                acc[j][0] += av * bv.x; acc[j][1] += av * bv.y;
                acc[j][2] += av * bv.z; acc[j][3] += av * bv.w;
            }
        }
    }
    float* pdb = pd + (size_t)b * N_ * N_;
    #pragma unroll
    for (int j = 0; j < 4; j++) {
        const int row = rb + tm + j;
        #pragma unroll
        for (int jj = 0; jj < 4; jj++)
            pdb[(size_t)row * N_ + cb + tn + jj] = 2.f * acc[j][jj];
    }
}

// ---------------------------------------------------------------- kNN phase 2:
// wave-per-point top-20 over d[j] = pd[i][j] - xx[j] (coalesced row reads,
// ballot-based lowest-index tie-break = lax.top_k order on sets).
__global__ __launch_bounds__(256) void k_sel(const float* __restrict__ pd,
                                             const float* __restrict__ xx,
                                             int* __restrict__ idx) {
    const int w = threadIdx.x >> 6, lane = threadIdx.x & 63;
    const int i = blockIdx.x * 4 + w;          // 0..8191
    const int b = i >> 10;
    const float* row = pd + (size_t)b * N_ * N_ + (size_t)(i & 1023) * N_;
    const float* xxb = xx + b * N_;
    float d[16];
    #pragma unroll
    for (int q = 0; q < 16; q++)
        d[q] = row[q * 64 + lane] - xxb[q * 64 + lane];
    int myj = 0;
    for (int kk = 0; kk < K_; kk++) {
        float v = d[0];
        #pragma unroll
        for (int u = 1; u < 16; u++) v = fmaxf(v, d[u]);
        #pragma unroll
        for (int s = 1; s < 64; s <<= 1) v = fmaxf(v, __shfl_xor(v, s, 64));
        int jw = -1;
        #pragma unroll
        for (int u = 0; u < 16; u++) {
            unsigned long long m = __ballot(d[u] == v);
            if (jw < 0 && m != 0ULL) jw = u * 64 + (int)__ffsll((long long)m) - 1;
        }
        if (jw < 0) jw = 0;                    // unreachable guard
        if (lane == kk) myj = jw;
        const int wq = jw >> 6, wl = jw & 63;
        #pragma unroll
        for (int u = 0; u < 16; u++)
            if (u == wq && lane == wl) d[u] = -3e38f;
    }
    if (lane < K_) idx[(size_t)i * K_ + lane] = myj;
}

// ---------------------------------------------------------------- GEMM
// C[8192][NC] = A[8192][KD] @ Bt[KD][NC] (+bias) ; optional q-scale on cols <
// scale_cols; optional residual. 64x64 tile, 4x4/thread, KT=32, K-remainder
// guarded at compile time (enables KD=3).
template<int KD, int NC>
__global__ __launch_bounds__(256) void k_gemm(const float* __restrict__ A,
                                              const float* __restrict__ Bt,
                                              const float* __restrict__ bias,
                                              const float* __restrict__ resid,
                                              float* __restrict__ Cout,
                                              int scale_cols, float qs) {
    const int t = threadIdx.x;
    const int rb = blockIdx.x * 64;
    const int cb = blockIdx.y * 64;
    __shared__ float As[64][33];
    __shared__ float Bs[32][68];
    float acc[4][4] = {};
    const int tm = (t >> 4) * 4, tn = (t & 15) * 4;
    for (int k0 = 0; k0 < KD; k0 += 32) {
        __syncthreads();
        #pragma unroll
        for (int u = t; u < 64 * 32; u += 256) {
            int m = u >> 5, k = u & 31;
            float av;
            if constexpr (KD % 32 == 0) av = A[(size_t)(rb + m) * KD + k0 + k];
            else av = (k0 + k < KD) ? A[(size_t)(rb + m) * KD + k0 + k] : 0.f;
            As[m][k] = av;
        }
        #pragma unroll
        for (int u = t; u < 32 * 64; u += 256) {
            int k = u >> 6, c = u & 63;
            float bvv;
            if constexpr (KD % 32 == 0) bvv = Bt[(size_t)(k0 + k) * NC + cb + c];
            else bvv = (k0 + k < KD) ? Bt[(size_t)(k0 + k) * NC + cb + c] : 0.f;
            Bs[k][c] = bvv;
        }
        __syncthreads();
        #pragma unroll
        for (int k = 0; k < 32; k++) {
            const float4 bv = *reinterpret_cast<const float4*>(&Bs[k][tn]);
            #pragma unroll
            for (int j = 0; j < 4; j++) {
                const float av = As[tm + j][k];
                acc[j][0] += av * bv.x; acc[j][1] += av * bv.y;
                acc[j][2] += av * bv.z; acc[j][3] += av * bv.w;
            }
        }
    }
    #pragma unroll
    for (int j = 0; j < 4; j++) {
        const int row = rb + tm + j;
        #pragma unroll
        for (int jj = 0; jj < 4; jj++) {
            const int col = cb + tn + jj;
            float v = acc[j][jj] + (bias ? bias[col] : 0.f);
            if (col < scale_cols) v *= qs;
            if (resid) v += resid[(size_t)row * NC + col];
            Cout[(size_t)row * NC + col] = v;
        }
    }
}

// ---------------------------------------------------------------- EdgeConv epilogue
// out[i] = lrelu(bn( max_k y[j_k] - y[i] + z[i] ))   (y=X@wn, z=X@wc)
template<int CO>
__global__ __launch_bounds__(256) void k_edgemax(const float* __restrict__ y,
                                                 const float* __restrict__ z,
                                                 const int* __restrict__ idx,
                                                 const float* __restrict__ g,
                                                 const float* __restrict__ bb,
                                                 float* __restrict__ out) {
    constexpr int TPP = CO / 4;          // threads per point
    constexpr int PPB = 256 / TPP;       // points per block (same batch: 1024%PPB==0)
    const int t = threadIdx.x;
    const int p = t / TPP;
    const int cw = (t % TPP) * 4;
    const int i0 = blockIdx.x * PPB;
    const int bbase = (i0 >> 10) << 10;
    __shared__ int sidx[PPB][K_];
    for (int u = t; u < PPB * K_; u += 256) {
        int pp = u / K_, kk = u - pp * K_;
        sidx[pp][kk] = idx[(size_t)(i0 + pp) * K_ + kk];
    }
    __syncthreads();
    const int ig = i0 + p;
    float4 m = {-3e38f, -3e38f, -3e38f, -3e38f};
    #pragma unroll 4
    for (int k = 0; k < K_; k++) {
        const int jg = bbase + sidx[p][k];
        const float4 yv = *reinterpret_cast<const float4*>(&y[(size_t)jg * CO + cw]);
        m.x = fmaxf(m.x, yv.x); m.y = fmaxf(m.y, yv.y);
        m.z = fmaxf(m.z, yv.z); m.w = fmaxf(m.w, yv.w);
    }
    const float4 yi = *reinterpret_cast<const float4*>(&y[(size_t)ig * CO + cw]);
    const float4 zi = *reinterpret_cast<const float4*>(&z[(size_t)ig * CO + cw]);
    const float4 gv = *reinterpret_cast<const float4*>(&g[cw]);
    const float4 bv = *reinterpret_cast<const float4*>(&bb[cw]);
    float vals[4] = {m.x - yi.x + zi.x, m.y - yi.y + zi.y,
                     m.z - yi.z + zi.z, m.w - yi.w + zi.w};
    float gs[4] = {gv.x, gv.y, gv.z, gv.w};
    float bs[4] = {bv.x, bv.y, bv.z, bv.w};
    float4 o;
    float* op = &o.x;
    #pragma unroll
    for (int j = 0; j < 4; j++) {
        float h = vals[j] * (gs[j] * BN_SCALE) + bs[j];
        op[j] = h >= 0.f ? h : 0.2f * h;
    }
    *reinterpret_cast<float4*>(&out[(size_t)ig * CO + cw]) = o;
}

// ---------------------------------------------------------------- attention (per n, 8x8 per head)
template<int E>
__global__ __launch_bounds__(256) void k_attn(const float* __restrict__ qkv,
                                              float* __restrict__ o) {
    constexpr int H = 4, D = E / H, L = 8;
    const int n = blockIdx.x;
    const int t = threadIdx.x;
    const int h = t >> 6, lane = t & 63;
    __shared__ float sq[L][3 * E];
    __shared__ float so[L][E];
    for (int u = t; u < L * 3 * E; u += 256) {
        int l = u / (3 * E), r = u - l * (3 * E);
        sq[l][r] = qkv[(size_t)(l * N_ + n) * (3 * E) + r];
    }
    __syncthreads();
    const int l = lane >> 3, m = lane & 7;
    float s = 0.f;
    #pragma unroll 8
    for (int dd = 0; dd < D; dd++)
        s += sq[l][h * D + dd] * sq[m][E + h * D + dd];
    float mx = s;
    #pragma unroll
    for (int st = 1; st < 8; st <<= 1) mx = fmaxf(mx, __shfl_xor(mx, st, 64));
    float e = expf(s - mx);
    float sum = e;
    #pragma unroll
    for (int st = 1; st < 8; st <<= 1) sum += __shfl_xor(sum, st, 64);
    const float p = e / sum;
    float pm[8];
    #pragma unroll
    for (int mm = 0; mm < 8; mm++) pm[mm] = __shfl(p, (lane & 56) | mm, 64);
    #pragma unroll
    for (int j = 0; j < D / 8; j++) {
        const int dd = m + 8 * j;
        float a = 0.f;
        #pragma unroll
        for (int mm = 0; mm < 8; mm++) a += pm[mm] * sq[mm][2 * E + h * D + dd];
        so[l][h * D + dd] = a;
    }
    __syncthreads();
    for (int u = t; u < L * E; u += 256) {
        int l2 = u / E, e2 = u - l2 * E;
        o[(size_t)(l2 * N_ + n) * E + e2] = so[l2][e2];
    }
}

// ---------------------------------------------------------------- conv5: cat(x1..x4) @ w5.T, BN, lrelu. 8 points/block.
__global__ __launch_bounds__(256) void k_conv5(const float* __restrict__ x1, const float* __restrict__ x2,
                                               const float* __restrict__ x3, const float* __restrict__ x4,
                                               const float* __restrict__ w5T,  // (512, 1024) fp32
                                               const float* __restrict__ g5,
                                               const float* __restrict__ b5,
                                               float* __restrict__ h5) {
    const int t = threadIdx.x;
    const int p0 = blockIdx.x * 8;
    __shared__ float cat[8][512];
    for (int u = t; u < 8 * 512; u += 256) {
        int p = u >> 9, c = u & 511;
        int pt = p0 + p;
        float v;
        if (c < 64)       v = x1[(size_t)pt * 64 + c];
        else if (c < 128) v = x2[(size_t)pt * 64 + (c - 64)];
        else if (c < 256) v = x3[(size_t)pt * 128 + (c - 128)];
        else              v = x4[(size_t)pt * 256 + (c - 256)];
        cat[p][c] = v;
    }
    __syncthreads();
    const int o = t * 4;
    float acc[8][4] = {};
    for (int c = 0; c < 512; c++) {
        const float4 wv = *reinterpret_cast<const float4*>(&w5T[(size_t)c * 1024 + o]);
        #pragma unroll
        for (int p = 0; p < 8; p++) {
            float cv = cat[p][c];
            acc[p][0] += cv * wv.x; acc[p][1] += cv * wv.y;
            acc[p][2] += cv * wv.z; acc[p][3] += cv * wv.w;
        }
    }
    #pragma unroll
    for (int p = 0; p < 8; p++) {
        #pragma unroll
        for (int j = 0; j < 4; j++) {
            int oo = o + j;
            float h = acc[p][j] * (g5[oo] * BN_SCALE) + b5[oo];
            h5[(size_t)(p0 + p) * 1024 + oo] = h >= 0.f ? h : 0.2f * h;
        }
    }
}

// ---------------------------------------------------------------- pool: max & mean over N per (b, channel)
__global__ __launch_bounds__(256) void k_pool(const float* __restrict__ h5, float* __restrict__ feat) {
    int c = blockIdx.x * 256 + threadIdx.x;   // 0..1023
    int b = blockIdx.y;
    float mx = -3e38f, sm = 0.f;
    for (int n = 0; n < N_; n++) {
        float v = h5[((size_t)b * N_ + n) * 1024 + c];
        mx = fmaxf(mx, v); sm += v;
    }
    feat[b * 2048 + c] = mx;
    feat[b * 2048 + 1024 + c] = sm * (1.f / 1024.f);
}

// ---------------------------------------------------------------- FC head
__global__ __launch_bounds__(256) void k_fc1(const float* __restrict__ feat, const float* __restrict__ l1wT,
                                             const float* __restrict__ g6, const float* __restrict__ b6,
                                             float* __restrict__ f1) {
    int b = blockIdx.x, t = threadIdx.x;
    __shared__ float fin[2048];
    for (int u = t; u < 2048; u += 256) fin[u] = feat[b * 2048 + u];
    __syncthreads();
    for (int o = t; o < 512; o += 256) {
        float acc = 0.f;
        for (int c = 0; c < 2048; c++) acc += fin[c] * l1wT[(size_t)c * 512 + o];
        float h = acc * (g6[o] * BN_SCALE) + b6[o];
        f1[b * 512 + o] = h >= 0.f ? h : 0.2f * h;
    }
}

__global__ __launch_bounds__(256) void k_fc2(const float* __restrict__ f1, const float* __restrict__ l2wT,
                                             const float* __restrict__ l2b,
                                             const float* __restrict__ g7, const float* __restrict__ b7,
                                             float* __restrict__ f2) {
    int b = blockIdx.x, t = threadIdx.x;
    __shared__ float fin[512];
    for (int u = t; u < 512; u += 256) fin[u] = f1[b * 512 + u];
    __syncthreads();
    if (t < 256) {
        int o = t;
        float acc = 0.f;
        for (int c = 0; c < 512; c++) acc += fin[c] * l2wT[(size_t)c * 256 + o];
        acc += l2b[o];
        float h = acc * (g7[o] * BN_SCALE) + b7[o];
        f2[b * 256 + o] = h >= 0.f ? h : 0.2f * h;
    }
}

__global__ __launch_bounds__(64) void k_fc3(const float* __restrict__ f2, const float* __restrict__ l3wT,
                                            const float* __restrict__ l3b,
                                            void* __restrict__ out, const int* __restrict__ flag) {
    int b = blockIdx.x, t = threadIdx.x;
    __shared__ float fin[256];
    for (int u = t; u < 256; u += 64) fin[u] = f2[b * 256 + u];
    __syncthreads();
    if (t < 40) {
        float acc = 0.f;
        for (int c = 0; c < 256; c++) acc += fin[c] * l3wT[(size_t)c * 40 + t];
        acc += l3b[t];
        if (*flag) ((__hip_bfloat16*)out)[b * 40 + t] = __float2bfloat16(acc);
        else       ((float*)out)[b * 40 + t] = acc;
    }
}

// ================================================================ host
extern "C" void kernel_launch(void* const* d_in, const int* in_sizes, int n_in,
                              void* d_out, int out_size, void* d_ws, size_t ws_size,
                              hipStream_t stream) {
    auto us = [&](int i) { return (const unsigned short*)d_in[i]; };

    float* ws = (float*)d_ws;
    size_t off = 0;
    auto A = [&](size_t n) { float* p = ws + off; off += (n + 3) & ~(size_t)3; return p; };
    float* xf0  = A((size_t)BN_ * 3);
    float* x1   = A((size_t)BN_ * 64);
    float* x2   = A((size_t)BN_ * 64);
    float* x3   = A((size_t)BN_ * 128);
    float* x4   = A((size_t)BN_ * 256);
    float* h5   = A((size_t)BN_ * 1024);   // also reused as pd scratch (8x1024x1024)
    float* feat = A(8 * 2048);
    float* f1   = A(8 * 512);
    float* f2   = A(8 * 256);
    float* xx   = A(BN_);
    int*   idx  = (int*)A((size_t)BN_ * K_);
    int*   flag = (int*)A(4);
    float* qkvw = A((size_t)BN_ * 768);   // qkv scratch / edge y
    float* ow   = A((size_t)BN_ * 256);   // attn-out scratch / edge z
    float* w1T   = A(6 * 64);
    float* w2T   = A(128 * 64);
    float* w3T   = A(128 * 128);
    float* w4T   = A(256 * 256);
    float* a1wiT = A(64 * 192);  float* a1woT = A(64 * 64);
    float* a2wiT = A(64 * 192);  float* a2woT = A(64 * 64);
    float* a3wiT = A(128 * 384); float* a3woT = A(128 * 128);
    float* a4wiT = A(256 * 768); float* a4woT = A(256 * 256);
    float* w5T   = A(512 * 1024);
    float* l1wT  = A(2048 * 512);
    float* l2wT  = A(512 * 256);
    float* l3wT  = A(256 * 40);
    // converted small vectors
    float* g1f = A(64);   float* b1f = A(64);
    float* g2f = A(64);   float* b2f = A(64);
    float* g3f = A(128);  float* b3f = A(128);
    float* g4f = A(256);  float* b4f = A(256);
    float* bi1 = A(192);  float* bo1 = A(64);
    float* bi2 = A(192);  float* bo2 = A(64);
    float* bi3 = A(384);  float* bo3 = A(128);
    float* bi4 = A(768);  float* bo4 = A(256);
    float* g5f = A(1024); float* b5f = A(1024);
    float* g6f = A(512);  float* b6f = A(512);
    float* l2bf = A(256);
    float* g7f = A(256);  float* b7f = A(256);
    float* l3bf = A(40);

    k_detect<<<1, 1, 0, stream>>>(us(2), us(5), us(8), us(11), us(30), us(33), us(37), flag);

    TList tl; int nb = 0; int k = 0;
    auto add = [&](int i, float* dst, int O, int I) {
        tl.p[k].src = d_in[i]; tl.p[k].dst = dst; tl.p[k].O = O; tl.p[k].I = I; tl.p[k].blk0 = nb;
        nb += (O * I + 255) / 256; k++;
    };
    add(0,  xf0,   BN_ * 3, 1);     // x convert (identity "transpose")
    add(1,  w1T,   64, 6);
    add(4,  w2T,   64, 128);
    add(7,  w3T,   128, 128);
    add(10, w4T,   256, 256);       // w4 is (256, 256): ci = 2*128
    add(13, a1wiT, 192, 64);
    add(15, a1woT, 64, 64);
    add(17, a2wiT, 192, 64);
    add(19, a2woT, 64, 64);
    add(21, a3wiT, 384, 128);
    add(23, a3woT, 128, 128);
    add(25, a4wiT, 768, 256);
    add(27, a4woT, 256, 256);
    add(29, w5T,   1024, 512);
    add(32, l1wT,  512, 2048);
    add(35, l2wT,  256, 512);
    add(39, l3wT,  40, 256);
    // vectors (identity convert)
    add(2,  g1f, 64, 1);   add(3,  b1f, 64, 1);
    add(5,  g2f, 64, 1);   add(6,  b2f, 64, 1);
    add(8,  g3f, 128, 1);  add(9,  b3f, 128, 1);
    add(11, g4f, 256, 1);  add(12, b4f, 256, 1);
    add(14, bi1, 192, 1);  add(16, bo1, 64, 1);
    add(18, bi2, 192, 1);  add(20, bo2, 64, 1);
    add(22, bi3, 384, 1);  add(24, bo3, 128, 1);
    add(26, bi4, 768, 1);  add(28, bo4, 256, 1);
    add(30, g5f, 1024, 1); add(31, b5f, 1024, 1);
    add(33, g6f, 512, 1);  add(34, b6f, 512, 1);
    add(36, l2bf, 256, 1);
    add(37, g7f, 256, 1);  add(38, b7f, 256, 1);
    add(40, l3bf, 40, 1);
    k_prep<<<nb, 256, 0, stream>>>(tl, k, flag);

    float* ye = qkvw;   // edge y scratch
    float* ze = ow;     // edge z scratch
    float* pd = h5;     // pd scratch (h5 is dead until conv5)
    const dim3 pdg(16, 16, 8);

    // layer 1  (C=3 -> 64)
    k_norms<<<BN_ / 256, 256, 0, stream>>>(xf0, xx, 3);
    k_pd<3><<<pdg, 256, 0, stream>>>(xf0, pd);
    k_sel<<<BN_ / 4, 256, 0, stream>>>(pd, xx, idx);
    k_gemm<3, 64><<<dim3(128, 1), 256, 0, stream>>>(xf0, w1T, nullptr, nullptr, ye, 0, 1.f);
    k_gemm<3, 64><<<dim3(128, 1), 256, 0, stream>>>(xf0, w1T + 3 * 64, nullptr, nullptr, ze, 0, 1.f);
    k_edgemax<64><<<BN_ / 16, 256, 0, stream>>>(ye, ze, idx, g1f, b1f, x1);
    k_gemm<64, 192><<<dim3(128, 3), 256, 0, stream>>>(x1, a1wiT, bi1, nullptr, qkvw, 64, 0.25f);
    k_attn<64><<<N_, 256, 0, stream>>>(qkvw, ow);
    k_gemm<64, 64><<<dim3(128, 1), 256, 0, stream>>>(ow, a1woT, bo1, x1, x1, 0, 1.f);

    // layer 2  (C=64 -> 64)
    k_norms<<<BN_ / 256, 256, 0, stream>>>(x1, xx, 64);
    k_pd<64><<<pdg, 256, 0, stream>>>(x1, pd);
    k_sel<<<BN_ / 4, 256, 0, stream>>>(pd, xx, idx);
    k_gemm<64, 64><<<dim3(128, 1), 256, 0, stream>>>(x1, w2T, nullptr, nullptr, ye, 0, 1.f);
    k_gemm<64, 64><<<dim3(128, 1), 256, 0, stream>>>(x1, w2T + 64 * 64, nullptr, nullptr, ze, 0, 1.f);
    k_edgemax<64><<<BN_ / 16, 256, 0, stream>>>(ye, ze, idx, g2f, b2f, x2);
    k_gemm<64, 192><<<dim3(128, 3), 256, 0, stream>>>(x2, a2wiT, bi2, nullptr, qkvw, 64, 0.25f);
    k_attn<64><<<N_, 256, 0, stream>>>(qkvw, ow);
    k_gemm<64, 64><<<dim3(128, 1), 256, 0, stream>>>(ow, a2woT, bo2, x2, x2, 0, 1.f);

    // layer 3  (C=64 -> 128)
    k_norms<<<BN_ / 256, 256, 0, stream>>>(x2, xx, 64);
    k_pd<64><<<pdg, 256, 0, stream>>>(x2, pd);
    k_sel<<<BN_ / 4, 256, 0, stream>>>(pd, xx, idx);
    k_gemm<64, 128><<<dim3(128, 2), 256, 0, stream>>>(x2, w3T, nullptr, nullptr, ye, 0, 1.f);
    k_gemm<64, 128><<<dim3(128, 2), 256, 0, stream>>>(x2, w3T + 64 * 128, nullptr, nullptr, ze, 0, 1.f);
    k_edgemax<128><<<BN_ / 8, 256, 0, stream>>>(ye, ze, idx, g3f, b3f, x3);
    k_gemm<128, 384><<<dim3(128, 6), 256, 0, stream>>>(x3, a3wiT, bi3, nullptr, qkvw, 128, 0.17677669529663687f);
    k_attn<128><<<N_, 256, 0, stream>>>(qkvw, ow);
    k_gemm<128, 128><<<dim3(128, 2), 256, 0, stream>>>(ow, a3woT, bo3, x3, x3, 0, 1.f);

    // layer 4  (C=128 -> 256)
    k_norms<<<BN_ / 256, 256, 0, stream>>>(x3, xx, 128);
    k_pd<128><<<pdg, 256, 0, stream>>>(x3, pd);
    k_sel<<<BN_ / 4, 256, 0, stream>>>(pd, xx, idx);
    k_gemm<128, 256><<<dim3(128, 4), 256, 0, stream>>>(x3, w4T, nullptr, nullptr, ye, 0, 1.f);
    k_gemm<128, 256><<<dim3(128, 4), 256, 0, stream>>>(x3, w4T + 128 * 256, nullptr, nullptr, ze, 0, 1.f);
    k_edgemax<256><<<BN_ / 4, 256, 0, stream>>>(ye, ze, idx, g4f, b4f, x4);
    k_gemm<256, 768><<<dim3(128, 12), 256, 0, stream>>>(x4, a4wiT, bi4, nullptr, qkvw, 256, 0.125f);
    k_attn<256><<<N_, 256, 0, stream>>>(qkvw, ow);
    k_gemm<256, 256><<<dim3(128, 4), 256, 0, stream>>>(ow, a4woT, bo4, x4, x4, 0, 1.f);

    // head
    k_conv5<<<BN_ / 8, 256, 0, stream>>>(x1, x2, x3, x4, w5T, g5f, b5f, h5);
    k_pool<<<dim3(4, 8), 256, 0, stream>>>(h5, feat);
    k_fc1<<<8, 256, 0, stream>>>(feat, l1wT, g6f, b6f, f1);
    k_fc2<<<8, 256, 0, stream>>>(f1, l2wT, l2bf, g7f, b7f, f2);
    k_fc3<<<8, 64, 0, stream>>>(f2, l3wT, l3bf, d_out, flag);
}